// Round 8
// baseline (195.343 us; speedup 1.0000x reference)
//
#include <hip/hip_runtime.h>
#include <stdint.h>

typedef __bf16 bf16;
typedef __bf16 bf16x4 __attribute__((ext_vector_type(4)));
typedef __bf16 bf16x8 __attribute__((ext_vector_type(8)));
typedef float f32x4 __attribute__((ext_vector_type(4)));

#define MFMA16(a, b, c) __builtin_amdgcn_mfma_f32_16x16x32_bf16((a), (b), (c), 0, 0, 0)

#define EMBED 1024
#define SEQ   2048
#define MROWS 4096
// 0.125 * log2(e): Q is pre-scaled so attn can use native v_exp_f32 (exp2).
#define ATTN_QSCALE 0.1803368801111f

__device__ __forceinline__ void gl2lds16(const bf16* g, bf16* l) {
    __builtin_amdgcn_global_load_lds(
        (const __attribute__((address_space(1))) void*)g,
        (__attribute__((address_space(3))) void*)l,
        16, 0, 0);
}

// ---------------------------------------------------------------------------
// fused fp32 -> bf16 cast of x + 4 weight matrices (contiguous dst region)
// ---------------------------------------------------------------------------
__global__ __launch_bounds__(256) void cast_all_kernel(
    const float* __restrict__ x,  const float* __restrict__ Wq,
    const float* __restrict__ Wk, const float* __restrict__ Wv,
    const float* __restrict__ Wo, bf16* __restrict__ dst) {
    const int blk = blockIdx.x;
    const float* src;
    size_t so, dofs;
    if (blk < 2048) {
        src = x; so = (size_t)blk * 2048; dofs = so;
    } else {
        const int w = (blk - 2048) >> 9;
        so  = (size_t)((blk - 2048) & 511) * 2048;
        src = (w == 0) ? Wq : (w == 1) ? Wk : (w == 2) ? Wv : Wo;
        dofs = (size_t)(4 + w) * 1024 * 1024 + so;
    }
    const size_t i = (size_t)threadIdx.x * 8;
    float4 a = *(const float4*)(src + so + i);
    float4 b = *(const float4*)(src + so + i + 4);
    bf16x8 o;
    o[0] = (bf16)a.x; o[1] = (bf16)a.y; o[2] = (bf16)a.z; o[3] = (bf16)a.w;
    o[4] = (bf16)b.x; o[5] = (bf16)b.y; o[6] = (bf16)b.z; o[7] = (bf16)b.w;
    *(bf16x8*)(dst + dofs + i) = o;
}

// ---------------------------------------------------------------------------
// Q/K GEMM path: 128x128 tile, BK=32, ring-3 (48 KB -> 3 blocks/CU), 2-deep
// counted vmcnt(4) pipeline.  3-term xor swizzle: 2-way bank aliasing (free).
// ---------------------------------------------------------------------------
template <bool SCALE>
__device__ __forceinline__ void gemm_tile(const bf16* __restrict__ A,
                                          const bf16* __restrict__ W,
                                          const float* __restrict__ bias,
                                          bf16* __restrict__ C,
                                          int m0, int n0, bf16* smem) {
    const int lane = threadIdx.x & 63;
    const int wv   = threadIdx.x >> 6;
    const int wm   = (wv >> 1) * 64;
    const int wn   = (wv & 1) * 64;
    const int fr   = lane & 15;
    const int quad = lane >> 4;
    const int srow = wv * 16 + (lane >> 2);
    const int swz  = ((lane & 3) ^ ((lane >> 2) & 3) ^ ((lane >> 4) & 3)) * 8;
    const int fcol = (quad ^ (fr & 3) ^ (fr >> 2)) * 8;

    f32x4 acc[4][4];
#pragma unroll
    for (int mt = 0; mt < 4; ++mt)
#pragma unroll
        for (int nt = 0; nt < 4; ++nt)
            acc[mt][nt] = (f32x4){0.f, 0.f, 0.f, 0.f};

    auto stage = [&](int kt, int bb) {
        bf16* As = smem + bb * 8192;
        bf16* Bs = As + 4096;
        const int k0 = kt * 32;
#pragma unroll
        for (int c = 0; c < 2; ++c) {
            gl2lds16(A + (size_t)(m0 + c * 64 + srow) * 1024 + k0 + swz,
                     &As[(c * 64 + wv * 16) * 32]);
            gl2lds16(W + (size_t)(n0 + c * 64 + srow) * 1024 + k0 + swz,
                     &Bs[(c * 64 + wv * 16) * 32]);
        }
    };

    stage(0, 0);
    stage(1, 1);
#pragma unroll
    for (int kt = 0; kt < 32; ++kt) {
        if (kt < 31) asm volatile("s_waitcnt vmcnt(4)" ::: "memory");
        else         asm volatile("s_waitcnt vmcnt(0)" ::: "memory");
        __builtin_amdgcn_s_barrier();
        if (kt < 30) stage(kt + 2, (kt + 2) % 3);
        const bf16* As = smem + (kt % 3) * 8192;
        const bf16* Bs = As + 4096;
        bf16x8 af[4], bfr[4];
#pragma unroll
        for (int t = 0; t < 4; ++t) {
            af[t]  = *(const bf16x8*)&As[(wm + t * 16 + fr) * 32 + fcol];
            bfr[t] = *(const bf16x8*)&Bs[(wn + t * 16 + fr) * 32 + fcol];
        }
        __builtin_amdgcn_s_setprio(1);
#pragma unroll
        for (int mt = 0; mt < 4; ++mt)
#pragma unroll
            for (int nt = 0; nt < 4; ++nt)
                acc[mt][nt] = MFMA16(af[mt], bfr[nt], acc[mt][nt]);
        __builtin_amdgcn_s_setprio(0);
    }

    float bv[4];
#pragma unroll
    for (int nt = 0; nt < 4; ++nt)
        bv[nt] = bias[n0 + wn + nt * 16 + fr];
    const int row4 = quad * 4;
#pragma unroll
    for (int mt = 0; mt < 4; ++mt)
#pragma unroll
        for (int nt = 0; nt < 4; ++nt)
#pragma unroll
            for (int r = 0; r < 4; ++r) {
                int m = m0 + wm + mt * 16 + row4 + r;
                int n = n0 + wn + nt * 16 + fr;
                float v = acc[mt][nt][r] + bv[nt];
                if (SCALE) v *= ATTN_QSCALE;
                C[(size_t)m * 1024 + n] = (bf16)v;
            }
}

// ---------------------------------------------------------------------------
// V^T GEMM path: swapped-operand MFMA + LDS round-trip transpose epilogue.
// Token axis of VT is PERMUTED within each 32-token chunk:
//   c' = quad*8 + t'*4 + r   <-  o = t'*16 + quad*4 + r
// Same BK=32 ring-3 pipeline + 3-term xor swizzle as gemm_tile.
// ---------------------------------------------------------------------------
__device__ __forceinline__ void v_tile(const bf16* __restrict__ x,
                                       const bf16* __restrict__ Wv,
                                       const float* __restrict__ bias,
                                       bf16* __restrict__ VT,
                                       int m0, int n0, bf16* smem) {
    const int lane = threadIdx.x & 63;
    const int wv   = threadIdx.x >> 6;
    const int wmW  = (wv >> 1) * 64;
    const int wnT  = (wv & 1) * 64;
    const int f    = lane & 15;
    const int quad = lane >> 4;
    const int srow = wv * 16 + (lane >> 2);
    const int swz  = ((lane & 3) ^ ((lane >> 2) & 3) ^ ((lane >> 4) & 3)) * 8;
    const int fcol = (quad ^ (f & 3) ^ (f >> 2)) * 8;

    f32x4 acc[4][4];
#pragma unroll
    for (int mt = 0; mt < 4; ++mt)
#pragma unroll
        for (int nt = 0; nt < 4; ++nt)
            acc[mt][nt] = (f32x4){0.f, 0.f, 0.f, 0.f};

    auto stage = [&](int kt, int bb) {
        bf16* As = smem + bb * 8192;
        bf16* Bs = As + 4096;
        const int k0 = kt * 32;
#pragma unroll
        for (int c = 0; c < 2; ++c) {
            gl2lds16(x  + (size_t)(m0 + c * 64 + srow) * 1024 + k0 + swz,
                     &As[(c * 64 + wv * 16) * 32]);
            gl2lds16(Wv + (size_t)(n0 + c * 64 + srow) * 1024 + k0 + swz,
                     &Bs[(c * 64 + wv * 16) * 32]);
        }
    };

    stage(0, 0);
    stage(1, 1);
#pragma unroll
    for (int kt = 0; kt < 32; ++kt) {
        if (kt < 31) asm volatile("s_waitcnt vmcnt(4)" ::: "memory");
        else         asm volatile("s_waitcnt vmcnt(0)" ::: "memory");
        __builtin_amdgcn_s_barrier();
        if (kt < 30) stage(kt + 2, (kt + 2) % 3);
        const bf16* As = smem + (kt % 3) * 8192;
        const bf16* Bs = As + 4096;
        bf16x8 wf[4], xf[4];
#pragma unroll
        for (int t = 0; t < 4; ++t) {
            wf[t] = *(const bf16x8*)&Bs[(wmW + t * 16 + f) * 32 + fcol];
            xf[t] = *(const bf16x8*)&As[(wnT + t * 16 + f) * 32 + fcol];
        }
        __builtin_amdgcn_s_setprio(1);
#pragma unroll
        for (int mt = 0; mt < 4; ++mt)
#pragma unroll
            for (int nt = 0; nt < 4; ++nt)
                acc[mt][nt] = MFMA16(wf[mt], xf[nt], acc[mt][nt]);
        __builtin_amdgcn_s_setprio(0);
    }

    float4 b4[4];
#pragma unroll
    for (int mt = 0; mt < 4; ++mt)
        b4[mt] = *(const float4*)&bias[n0 + wmW + mt * 16 + quad * 4];

    __syncthreads();   // all waves done computing before smem reuse as scratch

#pragma unroll
    for (int mt = 0; mt < 4; ++mt)
#pragma unroll
        for (int nt = 0; nt < 4; ++nt) {
            const int tok = wnT + nt * 16 + f;
#pragma unroll
            for (int r = 0; r < 4; ++r) {
                const float bvr = (r == 0) ? b4[mt].x : (r == 1) ? b4[mt].y
                                : (r == 2) ? b4[mt].z : b4[mt].w;
                smem[(wmW + mt * 16 + quad * 4 + r) * 136 + tok] =
                    (bf16)(acc[mt][nt][r] + bvr);
            }
        }
    __syncthreads();

    const int n_r  = threadIdx.x >> 4;
    const int t8   = (threadIdx.x & 15) * 8;       // permuted positions [t8, t8+8)
    const int base = t8 & ~31;                     // 32-token chunk base
    const int u4   = ((t8 >> 3) & 3) * 4;          // quad-group within chunk
    const int bb   = m0 >> 11;
    const int tokg = (m0 & 2047) + t8;
#pragma unroll
    for (int p = 0; p < 8; ++p) {
        const int n_loc = p * 16 + n_r;
        const bf16* row = &smem[n_loc * 136];
        bf16x4 a = *(const bf16x4*)&row[base + u4];         // orig tokens t'=0
        bf16x4 b = *(const bf16x4*)&row[base + 16 + u4];    // orig tokens t'=1
        bf16x8 v = {a[0], a[1], a[2], a[3], b[0], b[1], b[2], b[3]};
        *(bf16x8*)&VT[((size_t)(bb * 1024 + n0 + n_loc)) * 2048 + tokg] = v;
    }
}

// merged Q/K/V projection (plain mapping; 48 KB LDS -> 3 blocks/CU)
__global__ __launch_bounds__(256) void qkv_kernel(
    const bf16* __restrict__ x,
    const bf16* __restrict__ Wq, const float* __restrict__ bq,
    const bf16* __restrict__ Wk, const float* __restrict__ bk,
    const bf16* __restrict__ Wv, const float* __restrict__ bv,
    bf16* __restrict__ Q, bf16* __restrict__ K, bf16* __restrict__ VT) {
    __shared__ __align__(16) bf16 smem[24576];   // 3 bufs x (As 8KB + Bs 8KB)
    const int m0    = blockIdx.x * 128;
    const int which = blockIdx.y >> 3;
    const int n0    = (blockIdx.y & 7) * 128;
    if (which == 0)      gemm_tile<true>(x, Wq, bq, Q, m0, n0, smem);
    else if (which == 1) gemm_tile<false>(x, Wk, bk, K, m0, n0, smem);
    else                 v_tile(x, Wv, bv, VT, m0, n0, smem);
}

// ---------------------------------------------------------------------------
// O-proj GEMM, 128x64 tile, BK=32, ring-3 (36 KB -> 4 blocks/CU), 2-deep
// counted vmcnt(3) pipeline, fp32 out.
// ---------------------------------------------------------------------------
__global__ __launch_bounds__(256) void oproj_kernel(
    const bf16* __restrict__ A, const bf16* __restrict__ W,
    const float* __restrict__ bias, float* __restrict__ C) {
    const int m0 = blockIdx.x * 128;
    const int n0 = blockIdx.y * 64;

    __shared__ __align__(16) bf16 smem[18432];   // 3 bufs x (As 8KB + Bs 4KB)

    const int lane = threadIdx.x & 63;
    const int wv   = threadIdx.x >> 6;
    const int wm   = (wv >> 1) * 64;
    const int wn   = (wv & 1) * 32;
    const int fr   = lane & 15;
    const int quad = lane >> 4;
    const int srow = wv * 16 + (lane >> 2);
    const int swz  = ((lane & 3) ^ ((lane >> 2) & 3) ^ ((lane >> 4) & 3)) * 8;
    const int fcol = (quad ^ (fr & 3) ^ (fr >> 2)) * 8;

    f32x4 acc[4][2];
#pragma unroll
    for (int mt = 0; mt < 4; ++mt)
#pragma unroll
        for (int nt = 0; nt < 2; ++nt)
            acc[mt][nt] = (f32x4){0.f, 0.f, 0.f, 0.f};

    auto stage = [&](int kt, int bb) {
        bf16* As = smem + bb * 6144;
        bf16* Bs = As + 4096;
        const int k0 = kt * 32;
#pragma unroll
        for (int c = 0; c < 2; ++c)
            gl2lds16(A + (size_t)(m0 + c * 64 + srow) * 1024 + k0 + swz,
                     &As[(c * 64 + wv * 16) * 32]);
        gl2lds16(W + (size_t)(n0 + srow) * 1024 + k0 + swz,
                 &Bs[(wv * 16) * 32]);
    };

    stage(0, 0);
    stage(1, 1);
#pragma unroll
    for (int kt = 0; kt < 32; ++kt) {
        if (kt < 31) asm volatile("s_waitcnt vmcnt(3)" ::: "memory");
        else         asm volatile("s_waitcnt vmcnt(0)" ::: "memory");
        __builtin_amdgcn_s_barrier();
        if (kt < 30) stage(kt + 2, (kt + 2) % 3);
        const bf16* As = smem + (kt % 3) * 6144;
        const bf16* Bs = As + 4096;
        bf16x8 af[4], bfr[2];
#pragma unroll
        for (int t = 0; t < 4; ++t)
            af[t] = *(const bf16x8*)&As[(wm + t * 16 + fr) * 32 + fcol];
#pragma unroll
        for (int t = 0; t < 2; ++t)
            bfr[t] = *(const bf16x8*)&Bs[(wn + t * 16 + fr) * 32 + fcol];
        __builtin_amdgcn_s_setprio(1);
#pragma unroll
        for (int mt = 0; mt < 4; ++mt)
#pragma unroll
            for (int nt = 0; nt < 2; ++nt)
                acc[mt][nt] = MFMA16(af[mt], bfr[nt], acc[mt][nt]);
        __builtin_amdgcn_s_setprio(0);
    }

    float bv[2];
#pragma unroll
    for (int nt = 0; nt < 2; ++nt)
        bv[nt] = bias[n0 + wn + nt * 16 + fr];
    const int row4 = quad * 4;
#pragma unroll
    for (int mt = 0; mt < 4; ++mt)
#pragma unroll
        for (int nt = 0; nt < 2; ++nt)
#pragma unroll
            for (int r = 0; r < 4; ++r) {
                int m = m0 + wm + mt * 16 + row4 + r;
                int n = n0 + wn + nt * 16 + fr;
                C[(size_t)m * 1024 + n] = acc[mt][nt][r] + bv[nt];
            }
}

// ---------------------------------------------------------------------------
// Flash attention v15: q-tile 64 (16 q/wave, 1 group) -> 1024 blocks; ring-3
// LDS (48 KB -> 3 blocks/CU, 3 waves/SIMD).  Full KV per block (32 steps).
// Cross-tile pipeline QK(t+1)∥PV(t) kept; ring-3 forces stage-AFTER-barrier
// (stage(t+2) targets buffer (t-1)%3 whose readers all passed barrier t) and
// uniform vmcnt(0) (waits only the stage issued one full compute phase ago).
// QK split across u=0,1; exp split across u=2,3 (VALU spread between PV
// MFMA clusters).  In-register softmax normalize; writes final bf16 O.
// ---------------------------------------------------------------------------
__global__ __launch_bounds__(256, 3) void attn_kernel(
    const bf16* __restrict__ Q, const bf16* __restrict__ K,
    const bf16* __restrict__ VT, bf16* __restrict__ O) {
    const int tid  = threadIdx.x;
    const int lane = tid & 63;
    const int wv   = tid >> 6;       // 0..3
    const int quad = lane >> 4;
    const int f    = lane & 15;
    const int lin  = blockIdx.y * 32 + blockIdx.x;   // 0..1023
    const int sw   = (lin & 7) * 128 + (lin >> 3);   // XCD chunks of 128
    const int qt   = sw & 31;        // 32 q-tiles of 64
    const int bh   = sw >> 5;        // 0..31
    const int q0   = qt * 64;
    const int b    = bh >> 4;
    const int h    = bh & 15;

    const bf16* Qp = Q + ((size_t)b * SEQ) * 1024 + (size_t)h * 64;
    const bf16* Kp = K + ((size_t)b * SEQ) * 1024 + (size_t)h * 64;
    const bf16* Vp = VT + ((size_t)(b * 1024 + h * 64)) * 2048;   // [d][tok']
    bf16* Op = O + ((size_t)b * SEQ) * 1024 + (size_t)h * 64;

    __shared__ bf16 Ks[3][64 * 64];    // ring-3 [kv][d], swizzled 16B groups
    __shared__ bf16 VTs[3][64 * 64];   // ring-3 [d][kv'], swizzled 16B groups

    // Q fragments: wave handles 16 q-rows; pre-scaled by 0.125*log2e.
    bf16x8 qf0, qf1;
    {
        const bf16* qrow = Qp + (size_t)(q0 + wv * 16 + f) * 1024;
        qf0 = *(const bf16x8*)(qrow + quad * 8);
        qf1 = *(const bf16x8*)(qrow + 32 + quad * 8);
    }

    const int srow = wv * 8 + (lane >> 3);
    const int swz  = (((lane & 7) ^ ((lane >> 3) & 7))) * 8;
    auto stageK = [&](int t, int bb) {
        const int kv0 = t * 64;
#pragma unroll
        for (int i = 0; i < 2; ++i)
            gl2lds16(Kp + (size_t)(kv0 + i * 32 + srow) * 1024 + swz,
                     &Ks[bb][(i * 32 + wv * 8) * 64]);
    };
    auto stageVT = [&](int t, int bb) {
        const int kv0 = t * 64;
#pragma unroll
        for (int i = 0; i < 2; ++i)
            gl2lds16(Vp + (size_t)(i * 32 + srow) * 2048 + kv0 + swz,
                     &VTs[bb][(i * 32 + wv * 8) * 64]);
    };

    stageK(0, 0); stageVT(0, 0);
    stageK(1, 1); stageVT(1, 1);

    f32x4 oacc[4];
#pragma unroll
    for (int t = 0; t < 4; ++t)
        oacc[t] = (f32x4){0.f, 0.f, 0.f, 0.f};
    f32x4 lacc = (f32x4){0.f, 0.f, 0.f, 0.f};
    const bf16x8 ones8 = {(bf16)1.f, (bf16)1.f, (bf16)1.f, (bf16)1.f,
                          (bf16)1.f, (bf16)1.f, (bf16)1.f, (bf16)1.f};
    const f32x4  zero4 = (f32x4){0.f, 0.f, 0.f, 0.f};

    const int fcol0 = (quad ^ (f & 7)) * 8;
    const int fcol1 = ((4 + quad) ^ (f & 7)) * 8;

    bf16x8 pbA[2], pbB[2];

    // ---- prologue: wait tile 0 (tile 1's 4 loads may stay in flight),
    //      compute QK(0) -> pbA ----
    asm volatile("s_waitcnt vmcnt(4)" ::: "memory");
    __builtin_amdgcn_s_barrier();
    {
        f32x4 s[4];
        __builtin_amdgcn_s_setprio(1);
#pragma unroll
        for (int t4 = 0; t4 < 4; ++t4) {
            bf16x8 k0 = *(const bf16x8*)&Ks[0][(t4 * 16 + f) * 64 + fcol0];
            bf16x8 k1 = *(const bf16x8*)&Ks[0][(t4 * 16 + f) * 64 + fcol1];
            s[t4] = MFMA16(k0, qf0, zero4);
            s[t4] = MFMA16(k1, qf1, s[t4]);
        }
        __builtin_amdgcn_s_setprio(0);
#pragma unroll
        for (int kt = 0; kt < 2; ++kt) {
#pragma unroll
            for (int r = 0; r < 4; ++r) {
                pbA[kt][r]     = (bf16)__builtin_amdgcn_exp2f(s[2 * kt][r]);
                pbA[kt][4 + r] = (bf16)__builtin_amdgcn_exp2f(s[2 * kt + 1][r]);
            }
            lacc = MFMA16(ones8, pbA[kt], lacc);
        }
    }

    // step t: vmcnt(0) | barrier | stage(t+2) | QK(t+1)∥PV(t)
    auto step = [&](int t, bf16x8 (&pbc)[2], bf16x8 (&pbn)[2], bool doQK) {
        asm volatile("s_waitcnt vmcnt(0)" ::: "memory");
        __builtin_amdgcn_s_barrier();
        if (t < 30) { stageK(t + 2, (t + 2) % 3); stageVT(t + 2, (t + 2) % 3); }
        const int bq = (t + 1) % 3;
        const int bp = t % 3;

        f32x4 s[4];
#pragma unroll
        for (int u = 0; u < 4; ++u) {
            if (doQK && u < 2) {       // QK halves at u=0,1
                __builtin_amdgcn_s_setprio(1);
#pragma unroll
                for (int j = 0; j < 2; ++j) {
                    const int t4 = u * 2 + j;
                    bf16x8 k0 = *(const bf16x8*)&Ks[bq][(t4 * 16 + f) * 64 + fcol0];
                    bf16x8 k1 = *(const bf16x8*)&Ks[bq][(t4 * 16 + f) * 64 + fcol1];
                    s[t4] = MFMA16(k0, qf0, zero4);
                    s[t4] = MFMA16(k1, qf1, s[t4]);
                }
                __builtin_amdgcn_s_setprio(0);
            }
            // PV for d-tile u on tile t (P from previous tile's QK)
            __builtin_amdgcn_s_setprio(1);
#pragma unroll
            for (int kt = 0; kt < 2; ++kt) {
                const int pc = ((kt * 4 + quad) ^ (f & 7)) * 8;
                bf16x8 vf = *(const bf16x8*)&VTs[bp][(u * 16 + f) * 64 + pc];
                oacc[u] = MFMA16(vf, pbc[kt], oacc[u]);
            }
            __builtin_amdgcn_s_setprio(0);
            if (doQK && u >= 2) {      // exp halves at u=2,3
                const int kt = u - 2;
#pragma unroll
                for (int r = 0; r < 4; ++r) {
                    pbn[kt][r]     = (bf16)__builtin_amdgcn_exp2f(s[2 * kt][r]);
                    pbn[kt][4 + r] = (bf16)__builtin_amdgcn_exp2f(s[2 * kt + 1][r]);
                }
                lacc = MFMA16(ones8, pbn[kt], lacc);
            }
        }
    };

    for (int tt = 0; tt < 30; tt += 2) {
        step(tt,     pbA, pbB, true);
        step(tt + 1, pbB, pbA, true);
    }
    step(30, pbA, pbB, true);    // QK(31) -> pbB
    step(31, pbB, pbA, false);   // PV(31) only

    // ---- normalize in-register and store final bf16 O ----
    // lacc[r] = sum_k P[k][q-row f] for any r (ones-MFMA row-independent).
    {
        const float inv = 1.0f / lacc[0];
        const int q = q0 + wv * 16 + f;
        bf16* orow = Op + (size_t)q * 1024;
#pragma unroll
        for (int dt = 0; dt < 4; ++dt) {
            bf16x4 ov;
#pragma unroll
            for (int r = 0; r < 4; ++r)
                ov[r] = (bf16)(oacc[dt][r] * inv);
            *(bf16x4*)(orow + dt * 16 + quad * 4) = ov;
        }
    }
}

extern "C" void kernel_launch(void* const* d_in, const int* in_sizes, int n_in,
                              void* d_out, int out_size, void* d_ws, size_t ws_size,
                              hipStream_t stream) {
    const float* x  = (const float*)d_in[0];
    const float* Wq = (const float*)d_in[1];
    const float* bq = (const float*)d_in[2];
    const float* Wk = (const float*)d_in[3];
    const float* bk = (const float*)d_in[4];
    const float* Wv = (const float*)d_in[5];
    const float* bv = (const float*)d_in[6];
    const float* Wo = (const float*)d_in[7];
    const float* bo = (const float*)d_in[8];
    float* out = (float*)d_out;

    bf16* xb    = (bf16*)d_ws;
    bf16* Wqb   = xb   + (size_t)MROWS * 1024;
    bf16* Wkb   = Wqb  + (size_t)1024 * 1024;
    bf16* Wvb   = Wkb  + (size_t)1024 * 1024;
    bf16* Wob   = Wvb  + (size_t)1024 * 1024;
    bf16* Q     = Wob  + (size_t)1024 * 1024;
    bf16* K     = Q    + (size_t)MROWS * 1024;
    bf16* VT    = K    + (size_t)MROWS * 1024;   // [B*1024 rows][2048 tokens, permuted]
    bf16* O     = VT   + (size_t)MROWS * 1024;

    cast_all_kernel<<<4096, 256, 0, stream>>>(x, Wq, Wk, Wv, Wo, xb);

    qkv_kernel<<<dim3(32, 24), 256, 0, stream>>>(xb, Wqb, bq, Wkb, bk, Wvb, bv, Q, K, VT);
    attn_kernel<<<dim3(32, 32), 256, 0, stream>>>(Q, K, VT, O);
    oproj_kernel<<<dim3(32, 16), 256, 0, stream>>>(O, Wob, bo, out);
}

// Round 9
// 175.838 us; speedup vs baseline: 1.1109x; 1.1109x over previous
//
#include <hip/hip_runtime.h>
#include <stdint.h>

typedef __bf16 bf16;
typedef __bf16 bf16x4 __attribute__((ext_vector_type(4)));
typedef __bf16 bf16x8 __attribute__((ext_vector_type(8)));
typedef float f32x4 __attribute__((ext_vector_type(4)));

#define MFMA16(a, b, c) __builtin_amdgcn_mfma_f32_16x16x32_bf16((a), (b), (c), 0, 0, 0)

#define EMBED 1024
#define SEQ   2048
#define MROWS 4096
// 0.125 * log2(e): Q is pre-scaled so attn can use native v_exp_f32 (exp2).
#define ATTN_QSCALE 0.1803368801111f

__device__ __forceinline__ void gl2lds16(const bf16* g, bf16* l) {
    __builtin_amdgcn_global_load_lds(
        (const __attribute__((address_space(1))) void*)g,
        (__attribute__((address_space(3))) void*)l,
        16, 0, 0);
}

// ---------------------------------------------------------------------------
// fused fp32 -> bf16 cast of x + 4 weight matrices (contiguous dst region)
// ---------------------------------------------------------------------------
__global__ __launch_bounds__(256) void cast_all_kernel(
    const float* __restrict__ x,  const float* __restrict__ Wq,
    const float* __restrict__ Wk, const float* __restrict__ Wv,
    const float* __restrict__ Wo, bf16* __restrict__ dst) {
    const int blk = blockIdx.x;
    const float* src;
    size_t so, dofs;
    if (blk < 2048) {
        src = x; so = (size_t)blk * 2048; dofs = so;
    } else {
        const int w = (blk - 2048) >> 9;
        so  = (size_t)((blk - 2048) & 511) * 2048;
        src = (w == 0) ? Wq : (w == 1) ? Wk : (w == 2) ? Wv : Wo;
        dofs = (size_t)(4 + w) * 1024 * 1024 + so;
    }
    const size_t i = (size_t)threadIdx.x * 8;
    float4 a = *(const float4*)(src + so + i);
    float4 b = *(const float4*)(src + so + i + 4);
    bf16x8 o;
    o[0] = (bf16)a.x; o[1] = (bf16)a.y; o[2] = (bf16)a.z; o[3] = (bf16)a.w;
    o[4] = (bf16)b.x; o[5] = (bf16)b.y; o[6] = (bf16)b.z; o[7] = (bf16)b.w;
    *(bf16x8*)(dst + dofs + i) = o;
}

// ---------------------------------------------------------------------------
// Q/K GEMM path: 128x128 tile, BK=32, ring-3 (48 KB -> 3 blocks/CU), 2-deep
// counted vmcnt(4) pipeline.  3-term xor swizzle: 2-way bank aliasing (free).
// ---------------------------------------------------------------------------
template <bool SCALE>
__device__ __forceinline__ void gemm_tile(const bf16* __restrict__ A,
                                          const bf16* __restrict__ W,
                                          const float* __restrict__ bias,
                                          bf16* __restrict__ C,
                                          int m0, int n0, bf16* smem) {
    const int lane = threadIdx.x & 63;
    const int wv   = threadIdx.x >> 6;
    const int wm   = (wv >> 1) * 64;
    const int wn   = (wv & 1) * 64;
    const int fr   = lane & 15;
    const int quad = lane >> 4;
    const int srow = wv * 16 + (lane >> 2);
    const int swz  = ((lane & 3) ^ ((lane >> 2) & 3) ^ ((lane >> 4) & 3)) * 8;
    const int fcol = (quad ^ (fr & 3) ^ (fr >> 2)) * 8;

    f32x4 acc[4][4];
#pragma unroll
    for (int mt = 0; mt < 4; ++mt)
#pragma unroll
        for (int nt = 0; nt < 4; ++nt)
            acc[mt][nt] = (f32x4){0.f, 0.f, 0.f, 0.f};

    auto stage = [&](int kt, int bb) {
        bf16* As = smem + bb * 8192;
        bf16* Bs = As + 4096;
        const int k0 = kt * 32;
#pragma unroll
        for (int c = 0; c < 2; ++c) {
            gl2lds16(A + (size_t)(m0 + c * 64 + srow) * 1024 + k0 + swz,
                     &As[(c * 64 + wv * 16) * 32]);
            gl2lds16(W + (size_t)(n0 + c * 64 + srow) * 1024 + k0 + swz,
                     &Bs[(c * 64 + wv * 16) * 32]);
        }
    };

    stage(0, 0);
    stage(1, 1);
#pragma unroll
    for (int kt = 0; kt < 32; ++kt) {
        if (kt < 31) asm volatile("s_waitcnt vmcnt(4)" ::: "memory");
        else         asm volatile("s_waitcnt vmcnt(0)" ::: "memory");
        __builtin_amdgcn_s_barrier();
        if (kt < 30) stage(kt + 2, (kt + 2) % 3);
        const bf16* As = smem + (kt % 3) * 8192;
        const bf16* Bs = As + 4096;
        bf16x8 af[4], bfr[4];
#pragma unroll
        for (int t = 0; t < 4; ++t) {
            af[t]  = *(const bf16x8*)&As[(wm + t * 16 + fr) * 32 + fcol];
            bfr[t] = *(const bf16x8*)&Bs[(wn + t * 16 + fr) * 32 + fcol];
        }
        __builtin_amdgcn_s_setprio(1);
#pragma unroll
        for (int mt = 0; mt < 4; ++mt)
#pragma unroll
            for (int nt = 0; nt < 4; ++nt)
                acc[mt][nt] = MFMA16(af[mt], bfr[nt], acc[mt][nt]);
        __builtin_amdgcn_s_setprio(0);
    }

    float bv[4];
#pragma unroll
    for (int nt = 0; nt < 4; ++nt)
        bv[nt] = bias[n0 + wn + nt * 16 + fr];
    const int row4 = quad * 4;
#pragma unroll
    for (int mt = 0; mt < 4; ++mt)
#pragma unroll
        for (int nt = 0; nt < 4; ++nt)
#pragma unroll
            for (int r = 0; r < 4; ++r) {
                int m = m0 + wm + mt * 16 + row4 + r;
                int n = n0 + wn + nt * 16 + fr;
                float v = acc[mt][nt][r] + bv[nt];
                if (SCALE) v *= ATTN_QSCALE;
                C[(size_t)m * 1024 + n] = (bf16)v;
            }
}

// ---------------------------------------------------------------------------
// V^T GEMM path: swapped-operand MFMA + LDS round-trip transpose epilogue.
// Token axis of VT is PERMUTED within each 32-token chunk:
//   c' = quad*8 + t'*4 + r   <-  o = t'*16 + quad*4 + r
// Same BK=32 ring-3 pipeline + 3-term xor swizzle as gemm_tile.
// ---------------------------------------------------------------------------
__device__ __forceinline__ void v_tile(const bf16* __restrict__ x,
                                       const bf16* __restrict__ Wv,
                                       const float* __restrict__ bias,
                                       bf16* __restrict__ VT,
                                       int m0, int n0, bf16* smem) {
    const int lane = threadIdx.x & 63;
    const int wv   = threadIdx.x >> 6;
    const int wmW  = (wv >> 1) * 64;
    const int wnT  = (wv & 1) * 64;
    const int f    = lane & 15;
    const int quad = lane >> 4;
    const int srow = wv * 16 + (lane >> 2);
    const int swz  = ((lane & 3) ^ ((lane >> 2) & 3) ^ ((lane >> 4) & 3)) * 8;
    const int fcol = (quad ^ (f & 3) ^ (f >> 2)) * 8;

    f32x4 acc[4][4];
#pragma unroll
    for (int mt = 0; mt < 4; ++mt)
#pragma unroll
        for (int nt = 0; nt < 4; ++nt)
            acc[mt][nt] = (f32x4){0.f, 0.f, 0.f, 0.f};

    auto stage = [&](int kt, int bb) {
        bf16* As = smem + bb * 8192;
        bf16* Bs = As + 4096;
        const int k0 = kt * 32;
#pragma unroll
        for (int c = 0; c < 2; ++c) {
            gl2lds16(x  + (size_t)(m0 + c * 64 + srow) * 1024 + k0 + swz,
                     &As[(c * 64 + wv * 16) * 32]);
            gl2lds16(Wv + (size_t)(n0 + c * 64 + srow) * 1024 + k0 + swz,
                     &Bs[(c * 64 + wv * 16) * 32]);
        }
    };

    stage(0, 0);
    stage(1, 1);
#pragma unroll
    for (int kt = 0; kt < 32; ++kt) {
        if (kt < 31) asm volatile("s_waitcnt vmcnt(4)" ::: "memory");
        else         asm volatile("s_waitcnt vmcnt(0)" ::: "memory");
        __builtin_amdgcn_s_barrier();
        if (kt < 30) stage(kt + 2, (kt + 2) % 3);
        const bf16* As = smem + (kt % 3) * 8192;
        const bf16* Bs = As + 4096;
        bf16x8 wf[4], xf[4];
#pragma unroll
        for (int t = 0; t < 4; ++t) {
            wf[t] = *(const bf16x8*)&Bs[(wmW + t * 16 + f) * 32 + fcol];
            xf[t] = *(const bf16x8*)&As[(wnT + t * 16 + f) * 32 + fcol];
        }
        __builtin_amdgcn_s_setprio(1);
#pragma unroll
        for (int mt = 0; mt < 4; ++mt)
#pragma unroll
            for (int nt = 0; nt < 4; ++nt)
                acc[mt][nt] = MFMA16(wf[mt], xf[nt], acc[mt][nt]);
        __builtin_amdgcn_s_setprio(0);
    }

    float4 b4[4];
#pragma unroll
    for (int mt = 0; mt < 4; ++mt)
        b4[mt] = *(const float4*)&bias[n0 + wmW + mt * 16 + quad * 4];

    __syncthreads();   // all waves done computing before smem reuse as scratch

#pragma unroll
    for (int mt = 0; mt < 4; ++mt)
#pragma unroll
        for (int nt = 0; nt < 4; ++nt) {
            const int tok = wnT + nt * 16 + f;
#pragma unroll
            for (int r = 0; r < 4; ++r) {
                const float bvr = (r == 0) ? b4[mt].x : (r == 1) ? b4[mt].y
                                : (r == 2) ? b4[mt].z : b4[mt].w;
                smem[(wmW + mt * 16 + quad * 4 + r) * 136 + tok] =
                    (bf16)(acc[mt][nt][r] + bvr);
            }
        }
    __syncthreads();

    const int n_r  = threadIdx.x >> 4;
    const int t8   = (threadIdx.x & 15) * 8;       // permuted positions [t8, t8+8)
    const int base = t8 & ~31;                     // 32-token chunk base
    const int u4   = ((t8 >> 3) & 3) * 4;          // quad-group within chunk
    const int bb   = m0 >> 11;
    const int tokg = (m0 & 2047) + t8;
#pragma unroll
    for (int p = 0; p < 8; ++p) {
        const int n_loc = p * 16 + n_r;
        const bf16* row = &smem[n_loc * 136];
        bf16x4 a = *(const bf16x4*)&row[base + u4];         // orig tokens t'=0
        bf16x4 b = *(const bf16x4*)&row[base + 16 + u4];    // orig tokens t'=1
        bf16x8 v = {a[0], a[1], a[2], a[3], b[0], b[1], b[2], b[3]};
        *(bf16x8*)&VT[((size_t)(bb * 1024 + n0 + n_loc)) * 2048 + tokg] = v;
    }
}

// merged Q/K/V projection (plain mapping; 48 KB LDS -> 3 blocks/CU)
__global__ __launch_bounds__(256) void qkv_kernel(
    const bf16* __restrict__ x,
    const bf16* __restrict__ Wq, const float* __restrict__ bq,
    const bf16* __restrict__ Wk, const float* __restrict__ bk,
    const bf16* __restrict__ Wv, const float* __restrict__ bv,
    bf16* __restrict__ Q, bf16* __restrict__ K, bf16* __restrict__ VT) {
    __shared__ __align__(16) bf16 smem[24576];   // 3 bufs x (As 8KB + Bs 8KB)
    const int m0    = blockIdx.x * 128;
    const int which = blockIdx.y >> 3;
    const int n0    = (blockIdx.y & 7) * 128;
    if (which == 0)      gemm_tile<true>(x, Wq, bq, Q, m0, n0, smem);
    else if (which == 1) gemm_tile<false>(x, Wk, bk, K, m0, n0, smem);
    else                 v_tile(x, Wv, bv, VT, m0, n0, smem);
}

// ---------------------------------------------------------------------------
// O-proj GEMM, 128x64 tile, BK=32, ring-3 (36 KB -> 4 blocks/CU), 2-deep
// counted vmcnt(3) pipeline, fp32 out.
// ---------------------------------------------------------------------------
__global__ __launch_bounds__(256) void oproj_kernel(
    const bf16* __restrict__ A, const bf16* __restrict__ W,
    const float* __restrict__ bias, float* __restrict__ C) {
    const int m0 = blockIdx.x * 128;
    const int n0 = blockIdx.y * 64;

    __shared__ __align__(16) bf16 smem[18432];   // 3 bufs x (As 8KB + Bs 4KB)

    const int lane = threadIdx.x & 63;
    const int wv   = threadIdx.x >> 6;
    const int wm   = (wv >> 1) * 64;
    const int wn   = (wv & 1) * 32;
    const int fr   = lane & 15;
    const int quad = lane >> 4;
    const int srow = wv * 16 + (lane >> 2);
    const int swz  = ((lane & 3) ^ ((lane >> 2) & 3) ^ ((lane >> 4) & 3)) * 8;
    const int fcol = (quad ^ (fr & 3) ^ (fr >> 2)) * 8;

    f32x4 acc[4][2];
#pragma unroll
    for (int mt = 0; mt < 4; ++mt)
#pragma unroll
        for (int nt = 0; nt < 2; ++nt)
            acc[mt][nt] = (f32x4){0.f, 0.f, 0.f, 0.f};

    auto stage = [&](int kt, int bb) {
        bf16* As = smem + bb * 6144;
        bf16* Bs = As + 4096;
        const int k0 = kt * 32;
#pragma unroll
        for (int c = 0; c < 2; ++c)
            gl2lds16(A + (size_t)(m0 + c * 64 + srow) * 1024 + k0 + swz,
                     &As[(c * 64 + wv * 16) * 32]);
        gl2lds16(W + (size_t)(n0 + srow) * 1024 + k0 + swz,
                 &Bs[(wv * 16) * 32]);
    };

    stage(0, 0);
    stage(1, 1);
#pragma unroll
    for (int kt = 0; kt < 32; ++kt) {
        if (kt < 31) asm volatile("s_waitcnt vmcnt(3)" ::: "memory");
        else         asm volatile("s_waitcnt vmcnt(0)" ::: "memory");
        __builtin_amdgcn_s_barrier();
        if (kt < 30) stage(kt + 2, (kt + 2) % 3);
        const bf16* As = smem + (kt % 3) * 6144;
        const bf16* Bs = As + 4096;
        bf16x8 af[4], bfr[2];
#pragma unroll
        for (int t = 0; t < 4; ++t)
            af[t] = *(const bf16x8*)&As[(wm + t * 16 + fr) * 32 + fcol];
#pragma unroll
        for (int t = 0; t < 2; ++t)
            bfr[t] = *(const bf16x8*)&Bs[(wn + t * 16 + fr) * 32 + fcol];
        __builtin_amdgcn_s_setprio(1);
#pragma unroll
        for (int mt = 0; mt < 4; ++mt)
#pragma unroll
            for (int nt = 0; nt < 2; ++nt)
                acc[mt][nt] = MFMA16(af[mt], bfr[nt], acc[mt][nt]);
        __builtin_amdgcn_s_setprio(0);
    }

    float bv[2];
#pragma unroll
    for (int nt = 0; nt < 2; ++nt)
        bv[nt] = bias[n0 + wn + nt * 16 + fr];
    const int row4 = quad * 4;
#pragma unroll
    for (int mt = 0; mt < 4; ++mt)
#pragma unroll
        for (int nt = 0; nt < 2; ++nt)
#pragma unroll
            for (int r = 0; r < 4; ++r) {
                int m = m0 + wm + mt * 16 + row4 + r;
                int n = n0 + wn + nt * 16 + fr;
                C[(size_t)m * 1024 + n] = acc[mt][nt][r] + bv[nt];
            }
}

// ---------------------------------------------------------------------------
// Flash attention v16: v14's proven per-step structure (q-tile 128, 2 q-grps
// per wave, 72 MFMA/step, cross-tile QK(t+1)∥PV(t)) but ring-3 LDS (48 KB ->
// 3 blocks/CU, 3 waves/SIMD).  Schedule per step:
//   vmcnt(0) -> barrier -> stage(t+2) -> compute(t)
// Ring-3 safety: stage(t+2) targets (t+2)%3 == (t-1)%3, whose readers
// (compute(t-1)) all passed the barrier.  compute(t) reads tiles t and t+1,
// both fully staged and drained by the vmcnt(0)+barrier pair.  The stage has
// a full ~600-cyc MFMA phase of cover before its drain (unlike R8's 150cyc).
// In-register softmax normalize; writes final bf16 O.  512 blocks.
// ---------------------------------------------------------------------------
__global__ __launch_bounds__(256, 3) void attn_kernel(
    const bf16* __restrict__ Q, const bf16* __restrict__ K,
    const bf16* __restrict__ VT, bf16* __restrict__ O) {
    const int tid  = threadIdx.x;
    const int lane = tid & 63;
    const int wv   = tid >> 6;       // 0..3
    const int quad = lane >> 4;
    const int f    = lane & 15;
    const int lin  = blockIdx.y * 16 + blockIdx.x;   // 0..511
    const int sw   = (lin & 7) * 64 + (lin >> 3);    // XCD chunks of 64
    const int qt   = sw & 15;        // 16 q-tiles of 128
    const int bh   = sw >> 4;        // 0..31
    const int q0   = qt * 128;
    const int b    = bh >> 4;
    const int h    = bh & 15;

    const bf16* Qp = Q + ((size_t)b * SEQ) * 1024 + (size_t)h * 64;
    const bf16* Kp = K + ((size_t)b * SEQ) * 1024 + (size_t)h * 64;
    const bf16* Vp = VT + ((size_t)(b * 1024 + h * 64)) * 2048;   // [d][tok']
    bf16* Op = O + ((size_t)b * SEQ) * 1024 + (size_t)h * 64;

    __shared__ bf16 Ks[3][64 * 64];    // ring-3 [kv][d], swizzled 16B groups
    __shared__ bf16 VTs[3][64 * 64];   // ring-3 [d][kv'], swizzled 16B groups

    // Q fragments: wave handles 32 q-rows (2 groups of 16); pre-scaled.
    bf16x8 qf[2][2];
#pragma unroll
    for (int qg = 0; qg < 2; ++qg) {
        const bf16* qrow = Qp + (size_t)(q0 + wv * 32 + qg * 16 + f) * 1024;
        qf[qg][0] = *(const bf16x8*)(qrow + quad * 8);
        qf[qg][1] = *(const bf16x8*)(qrow + 32 + quad * 8);
    }

    const int srow = wv * 8 + (lane >> 3);
    const int swz  = (((lane & 7) ^ ((lane >> 3) & 7))) * 8;
    auto stageK = [&](int t, int bb) {
        const int kv0 = t * 64;
#pragma unroll
        for (int i = 0; i < 2; ++i)
            gl2lds16(Kp + (size_t)(kv0 + i * 32 + srow) * 1024 + swz,
                     &Ks[bb][(i * 32 + wv * 8) * 64]);
    };
    auto stageVT = [&](int t, int bb) {
        const int kv0 = t * 64;
#pragma unroll
        for (int i = 0; i < 2; ++i)
            gl2lds16(Vp + (size_t)(i * 32 + srow) * 2048 + kv0 + swz,
                     &VTs[bb][(i * 32 + wv * 8) * 64]);
    };

    stageK(0, 0); stageVT(0, 0);
    stageK(1, 1); stageVT(1, 1);

    f32x4 oacc[2][4];
#pragma unroll
    for (int qg = 0; qg < 2; ++qg)
#pragma unroll
        for (int t = 0; t < 4; ++t)
            oacc[qg][t] = (f32x4){0.f, 0.f, 0.f, 0.f};
    f32x4 lacc[2];
#pragma unroll
    for (int qg = 0; qg < 2; ++qg)
        lacc[qg] = (f32x4){0.f, 0.f, 0.f, 0.f};
    const bf16x8 ones8 = {(bf16)1.f, (bf16)1.f, (bf16)1.f, (bf16)1.f,
                          (bf16)1.f, (bf16)1.f, (bf16)1.f, (bf16)1.f};
    const f32x4  zero4 = (f32x4){0.f, 0.f, 0.f, 0.f};

    const int fcol0 = (quad ^ (f & 7)) * 8;
    const int fcol1 = ((4 + quad) ^ (f & 7)) * 8;

    bf16x8 pbA[2][2], pbB[2][2];

    // ---- prologue: drain tiles 0,1; compute QK(0) -> pbA ----
    asm volatile("s_waitcnt vmcnt(0)" ::: "memory");
    __builtin_amdgcn_s_barrier();
    {
        bf16x8 kf0[4], kf1[4];
#pragma unroll
        for (int t4 = 0; t4 < 4; ++t4) {
            kf0[t4] = *(const bf16x8*)&Ks[0][(t4 * 16 + f) * 64 + fcol0];
            kf1[t4] = *(const bf16x8*)&Ks[0][(t4 * 16 + f) * 64 + fcol1];
        }
#pragma unroll
        for (int qg = 0; qg < 2; ++qg) {
            f32x4 s[4];
            __builtin_amdgcn_s_setprio(1);
#pragma unroll
            for (int t4 = 0; t4 < 4; ++t4) {
                s[t4] = MFMA16(kf0[t4], qf[qg][0], zero4);
                s[t4] = MFMA16(kf1[t4], qf[qg][1], s[t4]);
            }
            __builtin_amdgcn_s_setprio(0);
#pragma unroll
            for (int kt = 0; kt < 2; ++kt) {
#pragma unroll
                for (int r = 0; r < 4; ++r) {
                    pbA[qg][kt][r]     = (bf16)__builtin_amdgcn_exp2f(s[2 * kt][r]);
                    pbA[qg][kt][4 + r] = (bf16)__builtin_amdgcn_exp2f(s[2 * kt + 1][r]);
                }
                lacc[qg] = MFMA16(ones8, pbA[qg][kt], lacc[qg]);
            }
        }
    }

    // step t: vmcnt(0) | barrier | stage(t+2) | QK(t+1)∥PV(t)
    auto step = [&](int t, bf16x8 (&pbc)[2][2], bf16x8 (&pbn)[2][2], bool doQK) {
        asm volatile("s_waitcnt vmcnt(0)" ::: "memory");
        __builtin_amdgcn_s_barrier();
        if (t < 30) { stageK(t + 2, (t + 2) % 3); stageVT(t + 2, (t + 2) % 3); }
        const int bq = (t + 1) % 3;
        const int bp = t % 3;

        bf16x8 kf0[4], kf1[4];
        if (doQK) {
#pragma unroll
            for (int t4 = 0; t4 < 4; ++t4) {
                kf0[t4] = *(const bf16x8*)&Ks[bq][(t4 * 16 + f) * 64 + fcol0];
                kf1[t4] = *(const bf16x8*)&Ks[bq][(t4 * 16 + f) * 64 + fcol1];
            }
        }
#pragma unroll
        for (int u = 0; u < 4; ++u) {
            f32x4 s[4];
            const bool qk = doQK && u < 2;
            if (qk) {
                __builtin_amdgcn_s_setprio(1);
#pragma unroll
                for (int t4 = 0; t4 < 4; ++t4) {
                    s[t4] = MFMA16(kf0[t4], qf[u][0], zero4);
                    s[t4] = MFMA16(kf1[t4], qf[u][1], s[t4]);
                }
                __builtin_amdgcn_s_setprio(0);
            }
            // PV for d-tile u on tile t (P from previous tile's QK)
            __builtin_amdgcn_s_setprio(1);
#pragma unroll
            for (int kt = 0; kt < 2; ++kt) {
                const int pc = ((kt * 4 + quad) ^ (f & 7)) * 8;
                bf16x8 vf = *(const bf16x8*)&VTs[bp][(u * 16 + f) * 64 + pc];
#pragma unroll
                for (int qg = 0; qg < 2; ++qg)
                    oacc[qg][u] = MFMA16(vf, pbc[qg][kt], oacc[qg][u]);
            }
            __builtin_amdgcn_s_setprio(0);
            if (qk) {
#pragma unroll
                for (int kt = 0; kt < 2; ++kt) {
#pragma unroll
                    for (int r = 0; r < 4; ++r) {
                        pbn[u][kt][r]     = (bf16)__builtin_amdgcn_exp2f(s[2 * kt][r]);
                        pbn[u][kt][4 + r] = (bf16)__builtin_amdgcn_exp2f(s[2 * kt + 1][r]);
                    }
                    lacc[u] = MFMA16(ones8, pbn[u][kt], lacc[u]);
                }
            }
        }
    };

    for (int tt = 0; tt < 30; tt += 2) {
        step(tt,     pbA, pbB, true);
        step(tt + 1, pbB, pbA, true);
    }
    step(30, pbA, pbB, true);    // QK(31) -> pbB (tile 31 staged at t=29)
    step(31, pbB, pbA, false);   // PV(31) only

    // ---- normalize in-register and store final bf16 O ----
    // lacc[qg][r] = sum_k P[k][q-row f] for any r (ones-MFMA row-independent).
#pragma unroll
    for (int qg = 0; qg < 2; ++qg) {
        const float inv = 1.0f / lacc[qg][0];
        const int q = q0 + wv * 32 + qg * 16 + f;
        bf16* orow = Op + (size_t)q * 1024;
#pragma unroll
        for (int dt = 0; dt < 4; ++dt) {
            bf16x4 ov;
#pragma unroll
            for (int r = 0; r < 4; ++r)
                ov[r] = (bf16)(oacc[qg][dt][r] * inv);
            *(bf16x4*)(orow + dt * 16 + quad * 4) = ov;
        }
    }
}

extern "C" void kernel_launch(void* const* d_in, const int* in_sizes, int n_in,
                              void* d_out, int out_size, void* d_ws, size_t ws_size,
                              hipStream_t stream) {
    const float* x  = (const float*)d_in[0];
    const float* Wq = (const float*)d_in[1];
    const float* bq = (const float*)d_in[2];
    const float* Wk = (const float*)d_in[3];
    const float* bk = (const float*)d_in[4];
    const float* Wv = (const float*)d_in[5];
    const float* bv = (const float*)d_in[6];
    const float* Wo = (const float*)d_in[7];
    const float* bo = (const float*)d_in[8];
    float* out = (float*)d_out;

    bf16* xb    = (bf16*)d_ws;
    bf16* Wqb   = xb   + (size_t)MROWS * 1024;
    bf16* Wkb   = Wqb  + (size_t)1024 * 1024;
    bf16* Wvb   = Wkb  + (size_t)1024 * 1024;
    bf16* Wob   = Wvb  + (size_t)1024 * 1024;
    bf16* Q     = Wob  + (size_t)1024 * 1024;
    bf16* K     = Q    + (size_t)MROWS * 1024;
    bf16* VT    = K    + (size_t)MROWS * 1024;   // [B*1024 rows][2048 tokens, permuted]
    bf16* O     = VT   + (size_t)MROWS * 1024;

    cast_all_kernel<<<4096, 256, 0, stream>>>(x, Wq, Wk, Wv, Wo, xb);

    qkv_kernel<<<dim3(32, 24), 256, 0, stream>>>(xb, Wqb, bq, Wkb, bk, Wvb, bv, Q, K, VT);
    attn_kernel<<<dim3(16, 32), 256, 0, stream>>>(Q, K, VT, O);
    oproj_kernel<<<dim3(32, 16), 256, 0, stream>>>(O, Wob, bo, out);
}

// Round 10
// 175.671 us; speedup vs baseline: 1.1120x; 1.0010x over previous
//
#include <hip/hip_runtime.h>
#include <stdint.h>

typedef __bf16 bf16;
typedef __bf16 bf16x4 __attribute__((ext_vector_type(4)));
typedef __bf16 bf16x8 __attribute__((ext_vector_type(8)));
typedef float f32x4 __attribute__((ext_vector_type(4)));

#define MFMA16(a, b, c) __builtin_amdgcn_mfma_f32_16x16x32_bf16((a), (b), (c), 0, 0, 0)

#define EMBED 1024
#define SEQ   2048
#define MROWS 4096
// 0.125 * log2(e): Q is pre-scaled so attn can use native v_exp_f32 (exp2).
#define ATTN_QSCALE 0.1803368801111f

__device__ __forceinline__ void gl2lds16(const bf16* g, bf16* l) {
    __builtin_amdgcn_global_load_lds(
        (const __attribute__((address_space(1))) void*)g,
        (__attribute__((address_space(3))) void*)l,
        16, 0, 0);
}

// ---------------------------------------------------------------------------
// fused fp32 -> bf16 cast of x + 4 weight matrices (contiguous dst region)
// ---------------------------------------------------------------------------
__global__ __launch_bounds__(256) void cast_all_kernel(
    const float* __restrict__ x,  const float* __restrict__ Wq,
    const float* __restrict__ Wk, const float* __restrict__ Wv,
    const float* __restrict__ Wo, bf16* __restrict__ dst) {
    const int blk = blockIdx.x;
    const float* src;
    size_t so, dofs;
    if (blk < 2048) {
        src = x; so = (size_t)blk * 2048; dofs = so;
    } else {
        const int w = (blk - 2048) >> 9;
        so  = (size_t)((blk - 2048) & 511) * 2048;
        src = (w == 0) ? Wq : (w == 1) ? Wk : (w == 2) ? Wv : Wo;
        dofs = (size_t)(4 + w) * 1024 * 1024 + so;
    }
    const size_t i = (size_t)threadIdx.x * 8;
    float4 a = *(const float4*)(src + so + i);
    float4 b = *(const float4*)(src + so + i + 4);
    bf16x8 o;
    o[0] = (bf16)a.x; o[1] = (bf16)a.y; o[2] = (bf16)a.z; o[3] = (bf16)a.w;
    o[4] = (bf16)b.x; o[5] = (bf16)b.y; o[6] = (bf16)b.z; o[7] = (bf16)b.w;
    *(bf16x8*)(dst + dofs + i) = o;
}

// ---------------------------------------------------------------------------
// Q/K GEMM path: 128x128 tile, BK=32, ring-3 (48 KB -> 3 blocks/CU), 2-deep
// counted vmcnt(4) pipeline.  3-term xor swizzle: 2-way bank aliasing (free).
// ---------------------------------------------------------------------------
template <bool SCALE>
__device__ __forceinline__ void gemm_tile(const bf16* __restrict__ A,
                                          const bf16* __restrict__ W,
                                          const float* __restrict__ bias,
                                          bf16* __restrict__ C,
                                          int m0, int n0, bf16* smem) {
    const int lane = threadIdx.x & 63;
    const int wv   = threadIdx.x >> 6;
    const int wm   = (wv >> 1) * 64;
    const int wn   = (wv & 1) * 64;
    const int fr   = lane & 15;
    const int quad = lane >> 4;
    const int srow = wv * 16 + (lane >> 2);
    const int swz  = ((lane & 3) ^ ((lane >> 2) & 3) ^ ((lane >> 4) & 3)) * 8;
    const int fcol = (quad ^ (fr & 3) ^ (fr >> 2)) * 8;

    f32x4 acc[4][4];
#pragma unroll
    for (int mt = 0; mt < 4; ++mt)
#pragma unroll
        for (int nt = 0; nt < 4; ++nt)
            acc[mt][nt] = (f32x4){0.f, 0.f, 0.f, 0.f};

    auto stage = [&](int kt, int bb) {
        bf16* As = smem + bb * 8192;
        bf16* Bs = As + 4096;
        const int k0 = kt * 32;
#pragma unroll
        for (int c = 0; c < 2; ++c) {
            gl2lds16(A + (size_t)(m0 + c * 64 + srow) * 1024 + k0 + swz,
                     &As[(c * 64 + wv * 16) * 32]);
            gl2lds16(W + (size_t)(n0 + c * 64 + srow) * 1024 + k0 + swz,
                     &Bs[(c * 64 + wv * 16) * 32]);
        }
    };

    stage(0, 0);
    stage(1, 1);
#pragma unroll
    for (int kt = 0; kt < 32; ++kt) {
        if (kt < 31) asm volatile("s_waitcnt vmcnt(4)" ::: "memory");
        else         asm volatile("s_waitcnt vmcnt(0)" ::: "memory");
        __builtin_amdgcn_s_barrier();
        if (kt < 30) stage(kt + 2, (kt + 2) % 3);
        const bf16* As = smem + (kt % 3) * 8192;
        const bf16* Bs = As + 4096;
        bf16x8 af[4], bfr[4];
#pragma unroll
        for (int t = 0; t < 4; ++t) {
            af[t]  = *(const bf16x8*)&As[(wm + t * 16 + fr) * 32 + fcol];
            bfr[t] = *(const bf16x8*)&Bs[(wn + t * 16 + fr) * 32 + fcol];
        }
        __builtin_amdgcn_s_setprio(1);
#pragma unroll
        for (int mt = 0; mt < 4; ++mt)
#pragma unroll
            for (int nt = 0; nt < 4; ++nt)
                acc[mt][nt] = MFMA16(af[mt], bfr[nt], acc[mt][nt]);
        __builtin_amdgcn_s_setprio(0);
    }

    float bv[4];
#pragma unroll
    for (int nt = 0; nt < 4; ++nt)
        bv[nt] = bias[n0 + wn + nt * 16 + fr];
    const int row4 = quad * 4;
#pragma unroll
    for (int mt = 0; mt < 4; ++mt)
#pragma unroll
        for (int nt = 0; nt < 4; ++nt)
#pragma unroll
            for (int r = 0; r < 4; ++r) {
                int m = m0 + wm + mt * 16 + row4 + r;
                int n = n0 + wn + nt * 16 + fr;
                float v = acc[mt][nt][r] + bv[nt];
                if (SCALE) v *= ATTN_QSCALE;
                C[(size_t)m * 1024 + n] = (bf16)v;
            }
}

// ---------------------------------------------------------------------------
// V^T GEMM path: swapped-operand MFMA + LDS round-trip transpose epilogue.
// Token axis of VT is PERMUTED within each 32-token chunk:
//   c' = quad*8 + t'*4 + r   <-  o = t'*16 + quad*4 + r
// Same BK=32 ring-3 pipeline + 3-term xor swizzle as gemm_tile.
// ---------------------------------------------------------------------------
__device__ __forceinline__ void v_tile(const bf16* __restrict__ x,
                                       const bf16* __restrict__ Wv,
                                       const float* __restrict__ bias,
                                       bf16* __restrict__ VT,
                                       int m0, int n0, bf16* smem) {
    const int lane = threadIdx.x & 63;
    const int wv   = threadIdx.x >> 6;
    const int wmW  = (wv >> 1) * 64;
    const int wnT  = (wv & 1) * 64;
    const int f    = lane & 15;
    const int quad = lane >> 4;
    const int srow = wv * 16 + (lane >> 2);
    const int swz  = ((lane & 3) ^ ((lane >> 2) & 3) ^ ((lane >> 4) & 3)) * 8;
    const int fcol = (quad ^ (f & 3) ^ (f >> 2)) * 8;

    f32x4 acc[4][4];
#pragma unroll
    for (int mt = 0; mt < 4; ++mt)
#pragma unroll
        for (int nt = 0; nt < 4; ++nt)
            acc[mt][nt] = (f32x4){0.f, 0.f, 0.f, 0.f};

    auto stage = [&](int kt, int bb) {
        bf16* As = smem + bb * 8192;
        bf16* Bs = As + 4096;
        const int k0 = kt * 32;
#pragma unroll
        for (int c = 0; c < 2; ++c) {
            gl2lds16(x  + (size_t)(m0 + c * 64 + srow) * 1024 + k0 + swz,
                     &As[(c * 64 + wv * 16) * 32]);
            gl2lds16(Wv + (size_t)(n0 + c * 64 + srow) * 1024 + k0 + swz,
                     &Bs[(c * 64 + wv * 16) * 32]);
        }
    };

    stage(0, 0);
    stage(1, 1);
#pragma unroll
    for (int kt = 0; kt < 32; ++kt) {
        if (kt < 31) asm volatile("s_waitcnt vmcnt(4)" ::: "memory");
        else         asm volatile("s_waitcnt vmcnt(0)" ::: "memory");
        __builtin_amdgcn_s_barrier();
        if (kt < 30) stage(kt + 2, (kt + 2) % 3);
        const bf16* As = smem + (kt % 3) * 8192;
        const bf16* Bs = As + 4096;
        bf16x8 wf[4], xf[4];
#pragma unroll
        for (int t = 0; t < 4; ++t) {
            wf[t] = *(const bf16x8*)&Bs[(wmW + t * 16 + f) * 32 + fcol];
            xf[t] = *(const bf16x8*)&As[(wnT + t * 16 + f) * 32 + fcol];
        }
        __builtin_amdgcn_s_setprio(1);
#pragma unroll
        for (int mt = 0; mt < 4; ++mt)
#pragma unroll
            for (int nt = 0; nt < 4; ++nt)
                acc[mt][nt] = MFMA16(wf[mt], xf[nt], acc[mt][nt]);
        __builtin_amdgcn_s_setprio(0);
    }

    float4 b4[4];
#pragma unroll
    for (int mt = 0; mt < 4; ++mt)
        b4[mt] = *(const float4*)&bias[n0 + wmW + mt * 16 + quad * 4];

    __syncthreads();   // all waves done computing before smem reuse as scratch

#pragma unroll
    for (int mt = 0; mt < 4; ++mt)
#pragma unroll
        for (int nt = 0; nt < 4; ++nt) {
            const int tok = wnT + nt * 16 + f;
#pragma unroll
            for (int r = 0; r < 4; ++r) {
                const float bvr = (r == 0) ? b4[mt].x : (r == 1) ? b4[mt].y
                                : (r == 2) ? b4[mt].z : b4[mt].w;
                smem[(wmW + mt * 16 + quad * 4 + r) * 136 + tok] =
                    (bf16)(acc[mt][nt][r] + bvr);
            }
        }
    __syncthreads();

    const int n_r  = threadIdx.x >> 4;
    const int t8   = (threadIdx.x & 15) * 8;       // permuted positions [t8, t8+8)
    const int base = t8 & ~31;                     // 32-token chunk base
    const int u4   = ((t8 >> 3) & 3) * 4;          // quad-group within chunk
    const int bb   = m0 >> 11;
    const int tokg = (m0 & 2047) + t8;
#pragma unroll
    for (int p = 0; p < 8; ++p) {
        const int n_loc = p * 16 + n_r;
        const bf16* row = &smem[n_loc * 136];
        bf16x4 a = *(const bf16x4*)&row[base + u4];         // orig tokens t'=0
        bf16x4 b = *(const bf16x4*)&row[base + 16 + u4];    // orig tokens t'=1
        bf16x8 v = {a[0], a[1], a[2], a[3], b[0], b[1], b[2], b[3]};
        *(bf16x8*)&VT[((size_t)(bb * 1024 + n0 + n_loc)) * 2048 + tokg] = v;
    }
}

// merged Q/K/V projection (plain mapping; 48 KB LDS -> 3 blocks/CU)
__global__ __launch_bounds__(256) void qkv_kernel(
    const bf16* __restrict__ x,
    const bf16* __restrict__ Wq, const float* __restrict__ bq,
    const bf16* __restrict__ Wk, const float* __restrict__ bk,
    const bf16* __restrict__ Wv, const float* __restrict__ bv,
    bf16* __restrict__ Q, bf16* __restrict__ K, bf16* __restrict__ VT) {
    __shared__ __align__(16) bf16 smem[24576];   // 3 bufs x (As 8KB + Bs 8KB)
    const int m0    = blockIdx.x * 128;
    const int which = blockIdx.y >> 3;
    const int n0    = (blockIdx.y & 7) * 128;
    if (which == 0)      gemm_tile<true>(x, Wq, bq, Q, m0, n0, smem);
    else if (which == 1) gemm_tile<false>(x, Wk, bk, K, m0, n0, smem);
    else                 v_tile(x, Wv, bv, VT, m0, n0, smem);
}

// ---------------------------------------------------------------------------
// O-proj GEMM, 128x64 tile, BK=32, ring-3 (36 KB -> 4 blocks/CU), 2-deep
// counted vmcnt(3) pipeline, fp32 out.
// ---------------------------------------------------------------------------
__global__ __launch_bounds__(256) void oproj_kernel(
    const bf16* __restrict__ A, const bf16* __restrict__ W,
    const float* __restrict__ bias, float* __restrict__ C) {
    const int m0 = blockIdx.x * 128;
    const int n0 = blockIdx.y * 64;

    __shared__ __align__(16) bf16 smem[18432];   // 3 bufs x (As 8KB + Bs 4KB)

    const int lane = threadIdx.x & 63;
    const int wv   = threadIdx.x >> 6;
    const int wm   = (wv >> 1) * 64;
    const int wn   = (wv & 1) * 32;
    const int fr   = lane & 15;
    const int quad = lane >> 4;
    const int srow = wv * 16 + (lane >> 2);
    const int swz  = ((lane & 3) ^ ((lane >> 2) & 3) ^ ((lane >> 4) & 3)) * 8;
    const int fcol = (quad ^ (fr & 3) ^ (fr >> 2)) * 8;

    f32x4 acc[4][2];
#pragma unroll
    for (int mt = 0; mt < 4; ++mt)
#pragma unroll
        for (int nt = 0; nt < 2; ++nt)
            acc[mt][nt] = (f32x4){0.f, 0.f, 0.f, 0.f};

    auto stage = [&](int kt, int bb) {
        bf16* As = smem + bb * 6144;
        bf16* Bs = As + 4096;
        const int k0 = kt * 32;
#pragma unroll
        for (int c = 0; c < 2; ++c)
            gl2lds16(A + (size_t)(m0 + c * 64 + srow) * 1024 + k0 + swz,
                     &As[(c * 64 + wv * 16) * 32]);
        gl2lds16(W + (size_t)(n0 + srow) * 1024 + k0 + swz,
                 &Bs[(wv * 16) * 32]);
    };

    stage(0, 0);
    stage(1, 1);
#pragma unroll
    for (int kt = 0; kt < 32; ++kt) {
        if (kt < 31) asm volatile("s_waitcnt vmcnt(3)" ::: "memory");
        else         asm volatile("s_waitcnt vmcnt(0)" ::: "memory");
        __builtin_amdgcn_s_barrier();
        if (kt < 30) stage(kt + 2, (kt + 2) % 3);
        const bf16* As = smem + (kt % 3) * 6144;
        const bf16* Bs = As + 4096;
        bf16x8 af[4], bfr[2];
#pragma unroll
        for (int t = 0; t < 4; ++t)
            af[t] = *(const bf16x8*)&As[(wm + t * 16 + fr) * 32 + fcol];
#pragma unroll
        for (int t = 0; t < 2; ++t)
            bfr[t] = *(const bf16x8*)&Bs[(wn + t * 16 + fr) * 32 + fcol];
        __builtin_amdgcn_s_setprio(1);
#pragma unroll
        for (int mt = 0; mt < 4; ++mt)
#pragma unroll
            for (int nt = 0; nt < 2; ++nt)
                acc[mt][nt] = MFMA16(af[mt], bfr[nt], acc[mt][nt]);
        __builtin_amdgcn_s_setprio(0);
    }

    float bv[2];
#pragma unroll
    for (int nt = 0; nt < 2; ++nt)
        bv[nt] = bias[n0 + wn + nt * 16 + fr];
    const int row4 = quad * 4;
#pragma unroll
    for (int mt = 0; mt < 4; ++mt)
#pragma unroll
        for (int nt = 0; nt < 2; ++nt)
#pragma unroll
            for (int r = 0; r < 4; ++r) {
                int m = m0 + wm + mt * 16 + row4 + r;
                int n = n0 + wn + nt * 16 + fr;
                C[(size_t)m * 1024 + n] = acc[mt][nt][r] + bv[nt];
            }
}

// ---------------------------------------------------------------------------
// Flash attention v14 (best-measured, restored from R7): FULL KV range per
// block (32 steps of 64), no combine, q-tile 128 (2 q-groups/wave),
// 512 blocks = 2/CU.  Ring-4 LDS, cross-tile QK(t+1)∥PV(t) pipeline with
// counted vmcnt(4) (stage(t+2) in flight over a full compute phase; tile
// t+1 guaranteed resident).  In-register softmax normalize -> final bf16 O.
// Occupancy experiments (R8: q-tile 64 @3blk; R9: ring-3 @3blk) both lost
// to this config -- per-step compute-per-wave is the binding constraint.
// ---------------------------------------------------------------------------
__global__ __launch_bounds__(256, 2) void attn_kernel(
    const bf16* __restrict__ Q, const bf16* __restrict__ K,
    const bf16* __restrict__ VT, bf16* __restrict__ O) {
    const int tid  = threadIdx.x;
    const int lane = tid & 63;
    const int wv   = tid >> 6;       // 0..3
    const int quad = lane >> 4;
    const int f    = lane & 15;
    const int lin  = blockIdx.y * 16 + blockIdx.x;   // 0..511
    const int sw   = (lin & 7) * 64 + (lin >> 3);    // XCD chunks of 64
    const int qt   = sw & 15;        // 16 q-tiles of 128
    const int bh   = sw >> 4;        // 0..31
    const int q0   = qt * 128;
    const int b    = bh >> 4;
    const int h    = bh & 15;

    const bf16* Qp = Q + ((size_t)b * SEQ) * 1024 + (size_t)h * 64;
    const bf16* Kp = K + ((size_t)b * SEQ) * 1024 + (size_t)h * 64;
    const bf16* Vp = VT + ((size_t)(b * 1024 + h * 64)) * 2048;   // [d][tok']
    bf16* Op = O + ((size_t)b * SEQ) * 1024 + (size_t)h * 64;

    __shared__ bf16 Ks[4][64 * 64];    // ring-4 [kv][d], swizzled 16B groups
    __shared__ bf16 VTs[4][64 * 64];   // ring-4 [d][kv'], swizzled 16B groups

    // Q fragments: wave handles 32 q-rows (2 groups of 16); pre-scaled.
    bf16x8 qf[2][2];
#pragma unroll
    for (int qg = 0; qg < 2; ++qg) {
        const bf16* qrow = Qp + (size_t)(q0 + wv * 32 + qg * 16 + f) * 1024;
        qf[qg][0] = *(const bf16x8*)(qrow + quad * 8);
        qf[qg][1] = *(const bf16x8*)(qrow + 32 + quad * 8);
    }

    const int srow = wv * 8 + (lane >> 3);
    const int swz  = (((lane & 7) ^ ((lane >> 3) & 7))) * 8;
    auto stageK = [&](int t, int bb) {
        const int kv0 = t * 64;
#pragma unroll
        for (int i = 0; i < 2; ++i)
            gl2lds16(Kp + (size_t)(kv0 + i * 32 + srow) * 1024 + swz,
                     &Ks[bb][(i * 32 + wv * 8) * 64]);
    };
    auto stageVT = [&](int t, int bb) {
        const int kv0 = t * 64;
#pragma unroll
        for (int i = 0; i < 2; ++i)
            gl2lds16(Vp + (size_t)(i * 32 + srow) * 2048 + kv0 + swz,
                     &VTs[bb][(i * 32 + wv * 8) * 64]);
    };

    stageK(0, 0); stageVT(0, 0);
    stageK(1, 1); stageVT(1, 1);

    f32x4 oacc[2][4];
#pragma unroll
    for (int qg = 0; qg < 2; ++qg)
#pragma unroll
        for (int t = 0; t < 4; ++t)
            oacc[qg][t] = (f32x4){0.f, 0.f, 0.f, 0.f};
    f32x4 lacc[2];
#pragma unroll
    for (int qg = 0; qg < 2; ++qg)
        lacc[qg] = (f32x4){0.f, 0.f, 0.f, 0.f};
    const bf16x8 ones8 = {(bf16)1.f, (bf16)1.f, (bf16)1.f, (bf16)1.f,
                          (bf16)1.f, (bf16)1.f, (bf16)1.f, (bf16)1.f};
    const f32x4  zero4 = (f32x4){0.f, 0.f, 0.f, 0.f};

    const int fcol0 = (quad ^ (f & 7)) * 8;
    const int fcol1 = ((4 + quad) ^ (f & 7)) * 8;

    bf16x8 pbA[2][2], pbB[2][2];

    // ---- prologue: wait tile 0, compute QK(0) -> pbA ----
    asm volatile("s_waitcnt vmcnt(4)" ::: "memory");
    __builtin_amdgcn_s_barrier();
    {
        bf16x8 kf0[4], kf1[4];
#pragma unroll
        for (int t4 = 0; t4 < 4; ++t4) {
            kf0[t4] = *(const bf16x8*)&Ks[0][(t4 * 16 + f) * 64 + fcol0];
            kf1[t4] = *(const bf16x8*)&Ks[0][(t4 * 16 + f) * 64 + fcol1];
        }
#pragma unroll
        for (int qg = 0; qg < 2; ++qg) {
            f32x4 s[4];
            __builtin_amdgcn_s_setprio(1);
#pragma unroll
            for (int t4 = 0; t4 < 4; ++t4) {
                s[t4] = MFMA16(kf0[t4], qf[qg][0], zero4);
                s[t4] = MFMA16(kf1[t4], qf[qg][1], s[t4]);
            }
            __builtin_amdgcn_s_setprio(0);
#pragma unroll
            for (int kt = 0; kt < 2; ++kt) {
#pragma unroll
                for (int r = 0; r < 4; ++r) {
                    pbA[qg][kt][r]     = (bf16)__builtin_amdgcn_exp2f(s[2 * kt][r]);
                    pbA[qg][kt][4 + r] = (bf16)__builtin_amdgcn_exp2f(s[2 * kt + 1][r]);
                }
                lacc[qg] = MFMA16(ones8, pbA[qg][kt], lacc[qg]);
            }
        }
    }

    // step t: stage(t+2) | wait tile t+1 (vmcnt 4) | barrier | QK(t+1)∥PV(t)
    auto step = [&](int t, bf16x8 (&pbc)[2][2], bf16x8 (&pbn)[2][2],
                    int drain, bool doStage, bool doQK) {
        if (doStage) { stageK(t + 2, (t + 2) & 3); stageVT(t + 2, (t + 2) & 3); }
        if (drain == 4) asm volatile("s_waitcnt vmcnt(4)" ::: "memory");
        else            asm volatile("s_waitcnt vmcnt(0)" ::: "memory");
        __builtin_amdgcn_s_barrier();
        const int bq = (t + 1) & 3;
        const int bp = t & 3;

        bf16x8 kf0[4], kf1[4];
        if (doQK) {
#pragma unroll
            for (int t4 = 0; t4 < 4; ++t4) {
                kf0[t4] = *(const bf16x8*)&Ks[bq][(t4 * 16 + f) * 64 + fcol0];
                kf1[t4] = *(const bf16x8*)&Ks[bq][(t4 * 16 + f) * 64 + fcol1];
            }
        }
#pragma unroll
        for (int u = 0; u < 4; ++u) {
            f32x4 s[4];
            const bool qk = doQK && u < 2;
            if (qk) {
                __builtin_amdgcn_s_setprio(1);
#pragma unroll
                for (int t4 = 0; t4 < 4; ++t4) {
                    s[t4] = MFMA16(kf0[t4], qf[u][0], zero4);
                    s[t4] = MFMA16(kf1[t4], qf[u][1], s[t4]);
                }
                __builtin_amdgcn_s_setprio(0);
            }
            // PV for d-tile u on tile t (P from previous tile's QK)
            __builtin_amdgcn_s_setprio(1);
#pragma unroll
            for (int kt = 0; kt < 2; ++kt) {
                const int pc = ((kt * 4 + quad) ^ (f & 7)) * 8;
                bf16x8 vf = *(const bf16x8*)&VTs[bp][(u * 16 + f) * 64 + pc];
#pragma unroll
                for (int qg = 0; qg < 2; ++qg)
                    oacc[qg][u] = MFMA16(vf, pbc[qg][kt], oacc[qg][u]);
            }
            __builtin_amdgcn_s_setprio(0);
            if (qk) {
#pragma unroll
                for (int kt = 0; kt < 2; ++kt) {
#pragma unroll
                    for (int r = 0; r < 4; ++r) {
                        pbn[u][kt][r]     = (bf16)__builtin_amdgcn_exp2f(s[2 * kt][r]);
                        pbn[u][kt][4 + r] = (bf16)__builtin_amdgcn_exp2f(s[2 * kt + 1][r]);
                    }
                    lacc[u] = MFMA16(ones8, pbn[u][kt], lacc[u]);
                }
            }
        }
    };

    for (int tt = 0; tt < 30; tt += 2) {
        step(tt,     pbA, pbB, 4, true, true);
        step(tt + 1, pbB, pbA, 4, true, true);
    }
    step(30, pbA, pbB, 0, false, true);   // waits tile 31; QK(31) -> pbB
    step(31, pbB, pbA, 0, false, false);  // PV(31) only

    // ---- normalize in-register and store final bf16 O ----
    // lacc[qg][r] = sum_k P[k][q-row f] for any r (ones-MFMA row-independent).
#pragma unroll
    for (int qg = 0; qg < 2; ++qg) {
        const float inv = 1.0f / lacc[qg][0];
        const int q = q0 + wv * 32 + qg * 16 + f;
        bf16* orow = Op + (size_t)q * 1024;
#pragma unroll
        for (int dt = 0; dt < 4; ++dt) {
            bf16x4 ov;
#pragma unroll
            for (int r = 0; r < 4; ++r)
                ov[r] = (bf16)(oacc[qg][dt][r] * inv);
            *(bf16x4*)(orow + dt * 16 + quad * 4) = ov;
        }
    }
}

extern "C" void kernel_launch(void* const* d_in, const int* in_sizes, int n_in,
                              void* d_out, int out_size, void* d_ws, size_t ws_size,
                              hipStream_t stream) {
    const float* x  = (const float*)d_in[0];
    const float* Wq = (const float*)d_in[1];
    const float* bq = (const float*)d_in[2];
    const float* Wk = (const float*)d_in[3];
    const float* bk = (const float*)d_in[4];
    const float* Wv = (const float*)d_in[5];
    const float* bv = (const float*)d_in[6];
    const float* Wo = (const float*)d_in[7];
    const float* bo = (const float*)d_in[8];
    float* out = (float*)d_out;

    bf16* xb    = (bf16*)d_ws;
    bf16* Wqb   = xb   + (size_t)MROWS * 1024;
    bf16* Wkb   = Wqb  + (size_t)1024 * 1024;
    bf16* Wvb   = Wkb  + (size_t)1024 * 1024;
    bf16* Wob   = Wvb  + (size_t)1024 * 1024;
    bf16* Q     = Wob  + (size_t)1024 * 1024;
    bf16* K     = Q    + (size_t)MROWS * 1024;
    bf16* VT    = K    + (size_t)MROWS * 1024;   // [B*1024 rows][2048 tokens, permuted]
    bf16* O     = VT   + (size_t)MROWS * 1024;

    cast_all_kernel<<<4096, 256, 0, stream>>>(x, Wq, Wk, Wv, Wo, xb);

    qkv_kernel<<<dim3(32, 24), 256, 0, stream>>>(xb, Wqb, bq, Wkb, bk, Wvb, bv, Q, K, VT);
    attn_kernel<<<dim3(16, 32), 256, 0, stream>>>(Q, K, VT, O);
    oproj_kernel<<<dim3(32, 16), 256, 0, stream>>>(O, Wob, bo, out);
}

// Round 11
// 173.461 us; speedup vs baseline: 1.1262x; 1.0127x over previous
//
#include <hip/hip_runtime.h>
#include <stdint.h>

typedef __bf16 bf16;
typedef __bf16 bf16x4 __attribute__((ext_vector_type(4)));
typedef __bf16 bf16x8 __attribute__((ext_vector_type(8)));
typedef float f32x4 __attribute__((ext_vector_type(4)));

#define MFMA16(a, b, c) __builtin_amdgcn_mfma_f32_16x16x32_bf16((a), (b), (c), 0, 0, 0)

#define EMBED 1024
#define SEQ   2048
#define MROWS 4096
// 0.125 * log2(e): Q is pre-scaled so attn can use native v_exp_f32 (exp2).
#define ATTN_QSCALE 0.1803368801111f

__device__ __forceinline__ void gl2lds16(const bf16* g, bf16* l) {
    __builtin_amdgcn_global_load_lds(
        (const __attribute__((address_space(1))) void*)g,
        (__attribute__((address_space(3))) void*)l,
        16, 0, 0);
}

// ---------------------------------------------------------------------------
// fused fp32 -> bf16 cast of x + 4 weight matrices (contiguous dst region)
// ---------------------------------------------------------------------------
__global__ __launch_bounds__(256) void cast_all_kernel(
    const float* __restrict__ x,  const float* __restrict__ Wq,
    const float* __restrict__ Wk, const float* __restrict__ Wv,
    const float* __restrict__ Wo, bf16* __restrict__ dst) {
    const int blk = blockIdx.x;
    const float* src;
    size_t so, dofs;
    if (blk < 2048) {
        src = x; so = (size_t)blk * 2048; dofs = so;
    } else {
        const int w = (blk - 2048) >> 9;
        so  = (size_t)((blk - 2048) & 511) * 2048;
        src = (w == 0) ? Wq : (w == 1) ? Wk : (w == 2) ? Wv : Wo;
        dofs = (size_t)(4 + w) * 1024 * 1024 + so;
    }
    const size_t i = (size_t)threadIdx.x * 8;
    float4 a = *(const float4*)(src + so + i);
    float4 b = *(const float4*)(src + so + i + 4);
    bf16x8 o;
    o[0] = (bf16)a.x; o[1] = (bf16)a.y; o[2] = (bf16)a.z; o[3] = (bf16)a.w;
    o[4] = (bf16)b.x; o[5] = (bf16)b.y; o[6] = (bf16)b.z; o[7] = (bf16)b.w;
    *(bf16x8*)(dst + dofs + i) = o;
}

// ---------------------------------------------------------------------------
// Q/K GEMM path v2: 256x128 tile, BK=32, ring-3 (72 KB -> 2 blocks/CU),
// 2-deep counted vmcnt(6) pipeline (6 gl2lds/thread/step: wait leaves tile
// t+1's 6 loads in flight, tile t guaranteed drained).  32 MFMA/step/wave
// (2x the 128x128 version) between the same 32 barriers -- halves per-MFMA
// barrier/waitcnt overhead.  Same verified 3-term xor swizzle (depends only
// on row mod 16 -> invariant under the BM change).
// ---------------------------------------------------------------------------
template <bool SCALE>
__device__ __forceinline__ void gemm_tile256(const bf16* __restrict__ A,
                                             const bf16* __restrict__ W,
                                             const float* __restrict__ bias,
                                             bf16* __restrict__ C,
                                             int m0, int n0, bf16* smem) {
    const int lane = threadIdx.x & 63;
    const int wv   = threadIdx.x >> 6;
    const int wm   = (wv >> 1) * 128;   // 2 wave-rows x 128
    const int wn   = (wv & 1) * 64;     // 2 wave-cols x 64
    const int fr   = lane & 15;
    const int quad = lane >> 4;
    const int srow = wv * 16 + (lane >> 2);
    const int swz  = ((lane & 3) ^ ((lane >> 2) & 3) ^ ((lane >> 4) & 3)) * 8;
    const int fcol = (quad ^ (fr & 3) ^ (fr >> 2)) * 8;

    f32x4 acc[8][4];
#pragma unroll
    for (int mt = 0; mt < 8; ++mt)
#pragma unroll
        for (int nt = 0; nt < 4; ++nt)
            acc[mt][nt] = (f32x4){0.f, 0.f, 0.f, 0.f};

    auto stage = [&](int kt, int bb) {
        bf16* As = smem + bb * 12288;   // 24KB/buffer: As 16KB + Bs 8KB
        bf16* Bs = As + 8192;
        const int k0 = kt * 32;
#pragma unroll
        for (int c = 0; c < 4; ++c)
            gl2lds16(A + (size_t)(m0 + c * 64 + srow) * 1024 + k0 + swz,
                     &As[(c * 64 + wv * 16) * 32]);
#pragma unroll
        for (int c = 0; c < 2; ++c)
            gl2lds16(W + (size_t)(n0 + c * 64 + srow) * 1024 + k0 + swz,
                     &Bs[(c * 64 + wv * 16) * 32]);
    };

    stage(0, 0);
    stage(1, 1);
#pragma unroll
    for (int kt = 0; kt < 32; ++kt) {
        if (kt < 31) asm volatile("s_waitcnt vmcnt(6)" ::: "memory");
        else         asm volatile("s_waitcnt vmcnt(0)" ::: "memory");
        __builtin_amdgcn_s_barrier();
        if (kt < 30) stage(kt + 2, (kt + 2) % 3);
        const bf16* As = smem + (kt % 3) * 12288;
        const bf16* Bs = As + 8192;
        bf16x8 bfr[4];
#pragma unroll
        for (int t = 0; t < 4; ++t)
            bfr[t] = *(const bf16x8*)&Bs[(wn + t * 16 + fr) * 32 + fcol];
        __builtin_amdgcn_s_setprio(1);
#pragma unroll
        for (int mt = 0; mt < 8; ++mt) {
            bf16x8 af = *(const bf16x8*)&As[(wm + mt * 16 + fr) * 32 + fcol];
#pragma unroll
            for (int nt = 0; nt < 4; ++nt)
                acc[mt][nt] = MFMA16(af, bfr[nt], acc[mt][nt]);
        }
        __builtin_amdgcn_s_setprio(0);
    }

    float bv[4];
#pragma unroll
    for (int nt = 0; nt < 4; ++nt)
        bv[nt] = bias[n0 + wn + nt * 16 + fr];
    const int row4 = quad * 4;
#pragma unroll
    for (int mt = 0; mt < 8; ++mt)
#pragma unroll
        for (int nt = 0; nt < 4; ++nt)
#pragma unroll
            for (int r = 0; r < 4; ++r) {
                int m = m0 + wm + mt * 16 + row4 + r;
                int n = n0 + wn + nt * 16 + fr;
                float v = acc[mt][nt][r] + bv[nt];
                if (SCALE) v *= ATTN_QSCALE;
                C[(size_t)m * 1024 + n] = (bf16)v;
            }
}

// ---------------------------------------------------------------------------
// V^T GEMM path: swapped-operand MFMA + LDS round-trip transpose epilogue.
// Token axis of VT is PERMUTED within each 32-token chunk:
//   c' = quad*8 + t'*4 + r   <-  o = t'*16 + quad*4 + r
// 128x128 tile, BK=32 ring-3, counted vmcnt(4), 3-term xor swizzle.
// ---------------------------------------------------------------------------
__device__ __forceinline__ void v_tile(const bf16* __restrict__ x,
                                       const bf16* __restrict__ Wv,
                                       const float* __restrict__ bias,
                                       bf16* __restrict__ VT,
                                       int m0, int n0, bf16* smem) {
    const int lane = threadIdx.x & 63;
    const int wv   = threadIdx.x >> 6;
    const int wmW  = (wv >> 1) * 64;
    const int wnT  = (wv & 1) * 64;
    const int f    = lane & 15;
    const int quad = lane >> 4;
    const int srow = wv * 16 + (lane >> 2);
    const int swz  = ((lane & 3) ^ ((lane >> 2) & 3) ^ ((lane >> 4) & 3)) * 8;
    const int fcol = (quad ^ (f & 3) ^ (f >> 2)) * 8;

    f32x4 acc[4][4];
#pragma unroll
    for (int mt = 0; mt < 4; ++mt)
#pragma unroll
        for (int nt = 0; nt < 4; ++nt)
            acc[mt][nt] = (f32x4){0.f, 0.f, 0.f, 0.f};

    auto stage = [&](int kt, int bb) {
        bf16* As = smem + bb * 8192;
        bf16* Bs = As + 4096;
        const int k0 = kt * 32;
#pragma unroll
        for (int c = 0; c < 2; ++c) {
            gl2lds16(x  + (size_t)(m0 + c * 64 + srow) * 1024 + k0 + swz,
                     &As[(c * 64 + wv * 16) * 32]);
            gl2lds16(Wv + (size_t)(n0 + c * 64 + srow) * 1024 + k0 + swz,
                     &Bs[(c * 64 + wv * 16) * 32]);
        }
    };

    stage(0, 0);
    stage(1, 1);
#pragma unroll
    for (int kt = 0; kt < 32; ++kt) {
        if (kt < 31) asm volatile("s_waitcnt vmcnt(4)" ::: "memory");
        else         asm volatile("s_waitcnt vmcnt(0)" ::: "memory");
        __builtin_amdgcn_s_barrier();
        if (kt < 30) stage(kt + 2, (kt + 2) % 3);
        const bf16* As = smem + (kt % 3) * 8192;
        const bf16* Bs = As + 4096;
        bf16x8 wf[4], xf[4];
#pragma unroll
        for (int t = 0; t < 4; ++t) {
            wf[t] = *(const bf16x8*)&Bs[(wmW + t * 16 + f) * 32 + fcol];
            xf[t] = *(const bf16x8*)&As[(wnT + t * 16 + f) * 32 + fcol];
        }
        __builtin_amdgcn_s_setprio(1);
#pragma unroll
        for (int mt = 0; mt < 4; ++mt)
#pragma unroll
            for (int nt = 0; nt < 4; ++nt)
                acc[mt][nt] = MFMA16(wf[mt], xf[nt], acc[mt][nt]);
        __builtin_amdgcn_s_setprio(0);
    }

    float4 b4[4];
#pragma unroll
    for (int mt = 0; mt < 4; ++mt)
        b4[mt] = *(const float4*)&bias[n0 + wmW + mt * 16 + quad * 4];

    __syncthreads();   // all waves done computing before smem reuse as scratch

#pragma unroll
    for (int mt = 0; mt < 4; ++mt)
#pragma unroll
        for (int nt = 0; nt < 4; ++nt) {
            const int tok = wnT + nt * 16 + f;
#pragma unroll
            for (int r = 0; r < 4; ++r) {
                const float bvr = (r == 0) ? b4[mt].x : (r == 1) ? b4[mt].y
                                : (r == 2) ? b4[mt].z : b4[mt].w;
                smem[(wmW + mt * 16 + quad * 4 + r) * 136 + tok] =
                    (bf16)(acc[mt][nt][r] + bvr);
            }
        }
    __syncthreads();

    const int n_r  = threadIdx.x >> 4;
    const int t8   = (threadIdx.x & 15) * 8;       // permuted positions [t8, t8+8)
    const int base = t8 & ~31;                     // 32-token chunk base
    const int u4   = ((t8 >> 3) & 3) * 4;          // quad-group within chunk
    const int bb   = m0 >> 11;
    const int tokg = (m0 & 2047) + t8;
#pragma unroll
    for (int p = 0; p < 8; ++p) {
        const int n_loc = p * 16 + n_r;
        const bf16* row = &smem[n_loc * 136];
        bf16x4 a = *(const bf16x4*)&row[base + u4];         // orig tokens t'=0
        bf16x4 b = *(const bf16x4*)&row[base + 16 + u4];    // orig tokens t'=1
        bf16x8 v = {a[0], a[1], a[2], a[3], b[0], b[1], b[2], b[3]};
        *(bf16x8*)&VT[((size_t)(bb * 1024 + n0 + n_loc)) * 2048 + tokg] = v;
    }
}

// merged Q/K/V projection: Q,K on 256x128 tiles (128 blocks each), V on
// 128x128 v_tile (256 blocks).  512 blocks total at 2/CU = all co-resident
// (zero tail wave).  LDS 72 KB (Q/K ring-3 of 24 KB; v_tile uses first 48 KB).
__global__ __launch_bounds__(256, 2) void qkv_kernel(
    const bf16* __restrict__ x,
    const bf16* __restrict__ Wq, const float* __restrict__ bq,
    const bf16* __restrict__ Wk, const float* __restrict__ bk,
    const bf16* __restrict__ Wv, const float* __restrict__ bv,
    bf16* __restrict__ Q, bf16* __restrict__ K, bf16* __restrict__ VT) {
    __shared__ __align__(16) bf16 smem[36864];   // 72 KB
    const int id = blockIdx.x;
    if (id < 128) {          // Q: 16 m-tiles x 8 n-tiles
        gemm_tile256<true>(x, Wq, bq, Q, (id >> 3) * 256, (id & 7) * 128, smem);
    } else if (id < 256) {   // K
        const int t = id - 128;
        gemm_tile256<false>(x, Wk, bk, K, (t >> 3) * 256, (t & 7) * 128, smem);
    } else {                 // V: 32 m-tiles x 8 n-tiles (128x128)
        const int t = id - 256;
        v_tile(x, Wv, bv, VT, (t >> 3) * 128, (t & 7) * 128, smem);
    }
}

// ---------------------------------------------------------------------------
// O-proj GEMM, 128x64 tile, BK=32, ring-3 (36 KB -> 4 blocks/CU), 2-deep
// counted vmcnt(3) pipeline, fp32 out.
// ---------------------------------------------------------------------------
__global__ __launch_bounds__(256) void oproj_kernel(
    const bf16* __restrict__ A, const bf16* __restrict__ W,
    const float* __restrict__ bias, float* __restrict__ C) {
    const int m0 = blockIdx.x * 128;
    const int n0 = blockIdx.y * 64;

    __shared__ __align__(16) bf16 smem[18432];   // 3 bufs x (As 8KB + Bs 4KB)

    const int lane = threadIdx.x & 63;
    const int wv   = threadIdx.x >> 6;
    const int wm   = (wv >> 1) * 64;
    const int wn   = (wv & 1) * 32;
    const int fr   = lane & 15;
    const int quad = lane >> 4;
    const int srow = wv * 16 + (lane >> 2);
    const int swz  = ((lane & 3) ^ ((lane >> 2) & 3) ^ ((lane >> 4) & 3)) * 8;
    const int fcol = (quad ^ (fr & 3) ^ (fr >> 2)) * 8;

    f32x4 acc[4][2];
#pragma unroll
    for (int mt = 0; mt < 4; ++mt)
#pragma unroll
        for (int nt = 0; nt < 2; ++nt)
            acc[mt][nt] = (f32x4){0.f, 0.f, 0.f, 0.f};

    auto stage = [&](int kt, int bb) {
        bf16* As = smem + bb * 6144;
        bf16* Bs = As + 4096;
        const int k0 = kt * 32;
#pragma unroll
        for (int c = 0; c < 2; ++c)
            gl2lds16(A + (size_t)(m0 + c * 64 + srow) * 1024 + k0 + swz,
                     &As[(c * 64 + wv * 16) * 32]);
        gl2lds16(W + (size_t)(n0 + srow) * 1024 + k0 + swz,
                 &Bs[(wv * 16) * 32]);
    };

    stage(0, 0);
    stage(1, 1);
#pragma unroll
    for (int kt = 0; kt < 32; ++kt) {
        if (kt < 31) asm volatile("s_waitcnt vmcnt(3)" ::: "memory");
        else         asm volatile("s_waitcnt vmcnt(0)" ::: "memory");
        __builtin_amdgcn_s_barrier();
        if (kt < 30) stage(kt + 2, (kt + 2) % 3);
        const bf16* As = smem + (kt % 3) * 6144;
        const bf16* Bs = As + 4096;
        bf16x8 af[4], bfr[2];
#pragma unroll
        for (int t = 0; t < 4; ++t)
            af[t] = *(const bf16x8*)&As[(wm + t * 16 + fr) * 32 + fcol];
#pragma unroll
        for (int t = 0; t < 2; ++t)
            bfr[t] = *(const bf16x8*)&Bs[(wn + t * 16 + fr) * 32 + fcol];
        __builtin_amdgcn_s_setprio(1);
#pragma unroll
        for (int mt = 0; mt < 4; ++mt)
#pragma unroll
            for (int nt = 0; nt < 2; ++nt)
                acc[mt][nt] = MFMA16(af[mt], bfr[nt], acc[mt][nt]);
        __builtin_amdgcn_s_setprio(0);
    }

    float bv[2];
#pragma unroll
    for (int nt = 0; nt < 2; ++nt)
        bv[nt] = bias[n0 + wn + nt * 16 + fr];
    const int row4 = quad * 4;
#pragma unroll
    for (int mt = 0; mt < 4; ++mt)
#pragma unroll
        for (int nt = 0; nt < 2; ++nt)
#pragma unroll
            for (int r = 0; r < 4; ++r) {
                int m = m0 + wm + mt * 16 + row4 + r;
                int n = n0 + wn + nt * 16 + fr;
                C[(size_t)m * 1024 + n] = acc[mt][nt][r] + bv[nt];
            }
}

// ---------------------------------------------------------------------------
// Flash attention v14 (best-measured): FULL KV range per block (32 steps of
// 64), no combine, q-tile 128 (2 q-groups/wave), 512 blocks = 2/CU.  Ring-4
// LDS, cross-tile QK(t+1)∥PV(t) pipeline with counted vmcnt(4).
// In-register softmax normalize -> final bf16 O.  Occupancy/q-tile/ring
// variants all measured within +-3% or worse (R5-R9); this is the optimum
// of the structure family.
// ---------------------------------------------------------------------------
__global__ __launch_bounds__(256, 2) void attn_kernel(
    const bf16* __restrict__ Q, const bf16* __restrict__ K,
    const bf16* __restrict__ VT, bf16* __restrict__ O) {
    const int tid  = threadIdx.x;
    const int lane = tid & 63;
    const int wv   = tid >> 6;       // 0..3
    const int quad = lane >> 4;
    const int f    = lane & 15;
    const int lin  = blockIdx.y * 16 + blockIdx.x;   // 0..511
    const int sw   = (lin & 7) * 64 + (lin >> 3);    // XCD chunks of 64
    const int qt   = sw & 15;        // 16 q-tiles of 128
    const int bh   = sw >> 4;        // 0..31
    const int q0   = qt * 128;
    const int b    = bh >> 4;
    const int h    = bh & 15;

    const bf16* Qp = Q + ((size_t)b * SEQ) * 1024 + (size_t)h * 64;
    const bf16* Kp = K + ((size_t)b * SEQ) * 1024 + (size_t)h * 64;
    const bf16* Vp = VT + ((size_t)(b * 1024 + h * 64)) * 2048;   // [d][tok']
    bf16* Op = O + ((size_t)b * SEQ) * 1024 + (size_t)h * 64;

    __shared__ bf16 Ks[4][64 * 64];    // ring-4 [kv][d], swizzled 16B groups
    __shared__ bf16 VTs[4][64 * 64];   // ring-4 [d][kv'], swizzled 16B groups

    // Q fragments: wave handles 32 q-rows (2 groups of 16); pre-scaled.
    bf16x8 qf[2][2];
#pragma unroll
    for (int qg = 0; qg < 2; ++qg) {
        const bf16* qrow = Qp + (size_t)(q0 + wv * 32 + qg * 16 + f) * 1024;
        qf[qg][0] = *(const bf16x8*)(qrow + quad * 8);
        qf[qg][1] = *(const bf16x8*)(qrow + 32 + quad * 8);
    }

    const int srow = wv * 8 + (lane >> 3);
    const int swz  = (((lane & 7) ^ ((lane >> 3) & 7))) * 8;
    auto stageK = [&](int t, int bb) {
        const int kv0 = t * 64;
#pragma unroll
        for (int i = 0; i < 2; ++i)
            gl2lds16(Kp + (size_t)(kv0 + i * 32 + srow) * 1024 + swz,
                     &Ks[bb][(i * 32 + wv * 8) * 64]);
    };
    auto stageVT = [&](int t, int bb) {
        const int kv0 = t * 64;
#pragma unroll
        for (int i = 0; i < 2; ++i)
            gl2lds16(Vp + (size_t)(i * 32 + srow) * 2048 + kv0 + swz,
                     &VTs[bb][(i * 32 + wv * 8) * 64]);
    };

    stageK(0, 0); stageVT(0, 0);
    stageK(1, 1); stageVT(1, 1);

    f32x4 oacc[2][4];
#pragma unroll
    for (int qg = 0; qg < 2; ++qg)
#pragma unroll
        for (int t = 0; t < 4; ++t)
            oacc[qg][t] = (f32x4){0.f, 0.f, 0.f, 0.f};
    f32x4 lacc[2];
#pragma unroll
    for (int qg = 0; qg < 2; ++qg)
        lacc[qg] = (f32x4){0.f, 0.f, 0.f, 0.f};
    const bf16x8 ones8 = {(bf16)1.f, (bf16)1.f, (bf16)1.f, (bf16)1.f,
                          (bf16)1.f, (bf16)1.f, (bf16)1.f, (bf16)1.f};
    const f32x4  zero4 = (f32x4){0.f, 0.f, 0.f, 0.f};

    const int fcol0 = (quad ^ (f & 7)) * 8;
    const int fcol1 = ((4 + quad) ^ (f & 7)) * 8;

    bf16x8 pbA[2][2], pbB[2][2];

    // ---- prologue: wait tile 0, compute QK(0) -> pbA ----
    asm volatile("s_waitcnt vmcnt(4)" ::: "memory");
    __builtin_amdgcn_s_barrier();
    {
        bf16x8 kf0[4], kf1[4];
#pragma unroll
        for (int t4 = 0; t4 < 4; ++t4) {
            kf0[t4] = *(const bf16x8*)&Ks[0][(t4 * 16 + f) * 64 + fcol0];
            kf1[t4] = *(const bf16x8*)&Ks[0][(t4 * 16 + f) * 64 + fcol1];
        }
#pragma unroll
        for (int qg = 0; qg < 2; ++qg) {
            f32x4 s[4];
            __builtin_amdgcn_s_setprio(1);
#pragma unroll
            for (int t4 = 0; t4 < 4; ++t4) {
                s[t4] = MFMA16(kf0[t4], qf[qg][0], zero4);
                s[t4] = MFMA16(kf1[t4], qf[qg][1], s[t4]);
            }
            __builtin_amdgcn_s_setprio(0);
#pragma unroll
            for (int kt = 0; kt < 2; ++kt) {
#pragma unroll
                for (int r = 0; r < 4; ++r) {
                    pbA[qg][kt][r]     = (bf16)__builtin_amdgcn_exp2f(s[2 * kt][r]);
                    pbA[qg][kt][4 + r] = (bf16)__builtin_amdgcn_exp2f(s[2 * kt + 1][r]);
                }
                lacc[qg] = MFMA16(ones8, pbA[qg][kt], lacc[qg]);
            }
        }
    }

    // step t: stage(t+2) | wait tile t+1 (vmcnt 4) | barrier | QK(t+1)∥PV(t)
    auto step = [&](int t, bf16x8 (&pbc)[2][2], bf16x8 (&pbn)[2][2],
                    int drain, bool doStage, bool doQK) {
        if (doStage) { stageK(t + 2, (t + 2) & 3); stageVT(t + 2, (t + 2) & 3); }
        if (drain == 4) asm volatile("s_waitcnt vmcnt(4)" ::: "memory");
        else            asm volatile("s_waitcnt vmcnt(0)" ::: "memory");
        __builtin_amdgcn_s_barrier();
        const int bq = (t + 1) & 3;
        const int bp = t & 3;

        bf16x8 kf0[4], kf1[4];
        if (doQK) {
#pragma unroll
            for (int t4 = 0; t4 < 4; ++t4) {
                kf0[t4] = *(const bf16x8*)&Ks[bq][(t4 * 16 + f) * 64 + fcol0];
                kf1[t4] = *(const bf16x8*)&Ks[bq][(t4 * 16 + f) * 64 + fcol1];
            }
        }
#pragma unroll
        for (int u = 0; u < 4; ++u) {
            f32x4 s[4];
            const bool qk = doQK && u < 2;
            if (qk) {
                __builtin_amdgcn_s_setprio(1);
#pragma unroll
                for (int t4 = 0; t4 < 4; ++t4) {
                    s[t4] = MFMA16(kf0[t4], qf[u][0], zero4);
                    s[t4] = MFMA16(kf1[t4], qf[u][1], s[t4]);
                }
                __builtin_amdgcn_s_setprio(0);
            }
            // PV for d-tile u on tile t (P from previous tile's QK)
            __builtin_amdgcn_s_setprio(1);
#pragma unroll
            for (int kt = 0; kt < 2; ++kt) {
                const int pc = ((kt * 4 + quad) ^ (f & 7)) * 8;
                bf16x8 vf = *(const bf16x8*)&VTs[bp][(u * 16 + f) * 64 + pc];
#pragma unroll
                for (int qg = 0; qg < 2; ++qg)
                    oacc[qg][u] = MFMA16(vf, pbc[qg][kt], oacc[qg][u]);
            }
            __builtin_amdgcn_s_setprio(0);
            if (qk) {
#pragma unroll
                for (int kt = 0; kt < 2; ++kt) {
#pragma unroll
                    for (int r = 0; r < 4; ++r) {
                        pbn[u][kt][r]     = (bf16)__builtin_amdgcn_exp2f(s[2 * kt][r]);
                        pbn[u][kt][4 + r] = (bf16)__builtin_amdgcn_exp2f(s[2 * kt + 1][r]);
                    }
                    lacc[u] = MFMA16(ones8, pbn[u][kt], lacc[u]);
                }
            }
        }
    };

    for (int tt = 0; tt < 30; tt += 2) {
        step(tt,     pbA, pbB, 4, true, true);
        step(tt + 1, pbB, pbA, 4, true, true);
    }
    step(30, pbA, pbB, 0, false, true);   // waits tile 31; QK(31) -> pbB
    step(31, pbB, pbA, 0, false, false);  // PV(31) only

    // ---- normalize in-register and store final bf16 O ----
    // lacc[qg][r] = sum_k P[k][q-row f] for any r (ones-MFMA row-independent).
#pragma unroll
    for (int qg = 0; qg < 2; ++qg) {
        const float inv = 1.0f / lacc[qg][0];
        const int q = q0 + wv * 32 + qg * 16 + f;
        bf16* orow = Op + (size_t)q * 1024;
#pragma unroll
        for (int dt = 0; dt < 4; ++dt) {
            bf16x4 ov;
#pragma unroll
            for (int r = 0; r < 4; ++r)
                ov[r] = (bf16)(oacc[qg][dt][r] * inv);
            *(bf16x4*)(orow + dt * 16 + quad * 4) = ov;
        }
    }
}

extern "C" void kernel_launch(void* const* d_in, const int* in_sizes, int n_in,
                              void* d_out, int out_size, void* d_ws, size_t ws_size,
                              hipStream_t stream) {
    const float* x  = (const float*)d_in[0];
    const float* Wq = (const float*)d_in[1];
    const float* bq = (const float*)d_in[2];
    const float* Wk = (const float*)d_in[3];
    const float* bk = (const float*)d_in[4];
    const float* Wv = (const float*)d_in[5];
    const float* bv = (const float*)d_in[6];
    const float* Wo = (const float*)d_in[7];
    const float* bo = (const float*)d_in[8];
    float* out = (float*)d_out;

    bf16* xb    = (bf16*)d_ws;
    bf16* Wqb   = xb   + (size_t)MROWS * 1024;
    bf16* Wkb   = Wqb  + (size_t)1024 * 1024;
    bf16* Wvb   = Wkb  + (size_t)1024 * 1024;
    bf16* Wob   = Wvb  + (size_t)1024 * 1024;
    bf16* Q     = Wob  + (size_t)1024 * 1024;
    bf16* K     = Q    + (size_t)MROWS * 1024;
    bf16* VT    = K    + (size_t)MROWS * 1024;   // [B*1024 rows][2048 tokens, permuted]
    bf16* O     = VT   + (size_t)MROWS * 1024;

    cast_all_kernel<<<4096, 256, 0, stream>>>(x, Wq, Wk, Wv, Wo, xb);

    qkv_kernel<<<512, 256, 0, stream>>>(xb, Wqb, bq, Wkb, bk, Wvb, bv, Q, K, VT);
    attn_kernel<<<dim3(16, 32), 256, 0, stream>>>(Q, K, VT, O);
    oproj_kernel<<<dim3(32, 16), 256, 0, stream>>>(O, Wob, bo, out);
}